// Round 3
// baseline (161.392 us; speedup 1.0000x reference)
//
#include <hip/hip_runtime.h>
#include <hip/hip_bf16.h>
#include <stdint.h>

#define B_ 16
#define Q_ 1800
#define C_ 256
#define WPR 29            // u64 words per adjacency row = ceil(1800/64)
#define OUT_SIG_ELEMS (B_*Q_*C_)
#define OUT_ELEMS (B_*Q_*C_ + 2*B_*Q_)

typedef unsigned long long u64;
typedef unsigned int u32;

// ---------------- K1a: sigmoid scores ----------------
__global__ void k_scores(const float* __restrict__ logits, float* __restrict__ scores) {
  int i = blockIdx.x * blockDim.x + threadIdx.x;
  if (i < B_ * Q_) {
    float x = logits[i];
    scores[i] = 1.0f / (1.0f + expf(-x));
  }
}

// ---------------- K1b: inverse L2 norms of signature rows --------------
__global__ void k_inv(const float* __restrict__ sig, float* __restrict__ inv) {
  int w = threadIdx.x >> 6, lane = threadIdx.x & 63;
  int row = blockIdx.x * 4 + w;
  if (row >= B_ * Q_) return;
  const float* p = sig + (size_t)row * C_;
  float4 v = *reinterpret_cast<const float4*>(p + lane * 4);
  float ss = v.x * v.x + v.y * v.y + v.z * v.z + v.w * v.w;
  #pragma unroll
  for (int m = 32; m; m >>= 1) ss += __shfl_xor(ss, m, 64);
  if (lane == 0) inv[row] = 1.0f / fmaxf(sqrtf(ss), 1e-12f);
}

// ---------------- K2: per-batch fallback + compaction of selected ------
__global__ __launch_bounds__(256)
void k_compact(const float* __restrict__ scores,
               int* __restrict__ sel_idx, int* __restrict__ sel_cnt) {
  int b = blockIdx.x, t = threadIdx.x;
  __shared__ int part[256];
  __shared__ u64 redk[256];
  const float* scb = scores + b * Q_;

  int f[8]; int cnt = 0; u64 mk = 0;
  #pragma unroll
  for (int e = 0; e < 8; ++e) {
    int q = t * 8 + e;
    int fl = 0;
    if (q < Q_) {
      float sc = scb[q];
      fl = (sc >= 0.5f) ? 1 : 0;
      u64 key = ((u64)__float_as_uint(sc) << 32) | (u32)(~(u32)q); // max score, min idx tie
      mk = (mk > key) ? mk : key;
    }
    f[e] = fl; cnt += fl;
  }
  part[t] = cnt; redk[t] = mk;
  __syncthreads();
  for (int s2 = 128; s2 > 0; s2 >>= 1) {
    if (t < s2) {
      part[t] += part[t + s2];
      redk[t] = (redk[t] > redk[t + s2]) ? redk[t] : redk[t + s2];
    }
    __syncthreads();
  }
  int total_sel = part[0];
  u64 kmax = redk[0];
  __syncthreads();

  if (total_sel == 0) {                    // fallback: argmax-score query
    int fb = (int)(~(u32)kmax);
    if (fb >= t * 8 && fb < t * 8 + 8) f[fb - t * 8] = 1;
  }
  cnt = 0;
  #pragma unroll
  for (int e = 0; e < 8; ++e) cnt += f[e];
  part[t] = cnt;
  __syncthreads();
  for (int s2 = 1; s2 < 256; s2 <<= 1) {   // Hillis-Steele inclusive scan
    int v = (t >= s2) ? part[t - s2] : 0;
    __syncthreads();
    part[t] += v;
    __syncthreads();
  }
  int excl = part[t] - cnt;
  #pragma unroll
  for (int e = 0; e < 8; ++e) {
    if (f[e]) { sel_idx[b * Q_ + excl] = t * 8 + e; excl++; }
  }
  if (t == 255) sel_cnt[b] = part[255];
}

// ---------------- K3: cosine-sim tiles over selected list -> adjacency bits
// adj lives in d_out (scratch phase); rewritten every launch before any read.
__global__ __launch_bounds__(256)
void k_sim(const float* __restrict__ sig, const float* __restrict__ inv,
           const int* __restrict__ sel_idx, const int* __restrict__ sel_cnt,
           u64* __restrict__ adj) {
  int b = blockIdx.z;
  int S = sel_cnt[b];
  int i0 = blockIdx.y * 64, j0 = blockIdx.x * 64;
  if (i0 >= S || j0 >= S) return;

  __shared__ float As[64][68];   // K-major: As[k][i]
  __shared__ float Bs[64][68];
  __shared__ u64 adjtile[64];

  const int t = threadIdx.x;
  const int ti = t & 15, tj = t >> 4;     // 16x16 threads -> 4x4 regs each
  const int lr = t >> 2, lq = t & 3;      // load mapping: 4 threads per row

  const float* sb = sig + (size_t)b * Q_ * C_;
  const int* sidx = sel_idx + b * Q_;
  const float* invb = inv + b * Q_;

  int gi = i0 + lr, gj = j0 + lr;
  int rowA = (gi < S) ? sidx[gi] : sidx[0];
  int rowB = (gj < S) ? sidx[gj] : sidx[0];
  float scA = (gi < S) ? invb[rowA] : 0.0f;   // OOR rows -> zeros -> sim 0
  float scB = (gj < S) ? invb[rowB] : 0.0f;

  float acc[4][4];
  #pragma unroll
  for (int a = 0; a < 4; ++a)
    #pragma unroll
    for (int c = 0; c < 4; ++c) acc[a][c] = 0.0f;

  for (int kc = 0; kc < 4; ++kc) {
    __syncthreads();
    #pragma unroll
    for (int m = 0; m < 4; ++m) {
      int kk = (m * 4 + lq) * 4;    // 0..60 step 4
      float4 va = *reinterpret_cast<const float4*>(sb + (size_t)rowA * C_ + kc * 64 + kk);
      As[kk + 0][lr] = va.x * scA; As[kk + 1][lr] = va.y * scA;
      As[kk + 2][lr] = va.z * scA; As[kk + 3][lr] = va.w * scA;
      float4 vb = *reinterpret_cast<const float4*>(sb + (size_t)rowB * C_ + kc * 64 + kk);
      Bs[kk + 0][lr] = vb.x * scB; Bs[kk + 1][lr] = vb.y * scB;
      Bs[kk + 2][lr] = vb.z * scB; Bs[kk + 3][lr] = vb.w * scB;
    }
    __syncthreads();
    #pragma unroll 8
    for (int k = 0; k < 64; ++k) {
      float4 a4 = *reinterpret_cast<const float4*>(&As[k][ti * 4]);
      float4 b4 = *reinterpret_cast<const float4*>(&Bs[k][tj * 4]);
      float av[4] = {a4.x, a4.y, a4.z, a4.w};
      float bv[4] = {b4.x, b4.y, b4.z, b4.w};
      #pragma unroll
      for (int a = 0; a < 4; ++a)
        #pragma unroll
        for (int c = 0; c < 4; ++c) acc[a][c] = fmaf(av[a], bv[c], acc[a][c]);
    }
  }

  if (t < 64) adjtile[t] = 0ull;
  __syncthreads();
  #pragma unroll
  for (int a = 0; a < 4; ++a) {
    #pragma unroll
    for (int c = 0; c < 4; ++c) {
      if (acc[a][c] >= 0.8f) atomicOr(&adjtile[ti * 4 + a], 1ull << (tj * 4 + c));
    }
  }
  __syncthreads();
  if (t < 64) {
    int gi2 = i0 + t;
    if (gi2 < S) adj[((size_t)b * Q_ + gi2) * WPR + blockIdx.x] = adjtile[t];
  }
}

// ---------------- K4: CC label propagation + best-per-component + compact
__global__ __launch_bounds__(256)
void k_cc(const float* __restrict__ scores, const int* __restrict__ sel_idx,
          const int* __restrict__ sel_cnt, const u64* __restrict__ adj,
          int* __restrict__ best_idx, float* __restrict__ best_sc,
          int* __restrict__ nroots) {
  int b = blockIdx.x, t = threadIdx.x;
  __shared__ int lab[Q_];
  __shared__ int lab2[Q_];
  __shared__ u64 best[Q_];
  __shared__ int part[256];
  __shared__ int s_changed;

  int S = sel_cnt[b];
  int nw = (S + 63) >> 6;
  const u64* arow0 = adj + (size_t)b * Q_ * WPR;

  for (int s = t; s < S; s += 256) lab[s] = s;
  __syncthreads();

  for (int iter = 0; iter < Q_ + 2; ++iter) {
    if (t == 0) s_changed = 0;
    __syncthreads();
    for (int s = t; s < S; s += 256) {
      int m = lab[s];
      const u64* row = arow0 + (size_t)s * WPR;
      for (int w = 0; w < nw; ++w) {
        u64 msk = row[w];
        while (msk) {
          int j = (w << 6) + __builtin_ctzll(msk);
          int lj = lab[j];
          m = (lj < m) ? lj : m;
          msk &= msk - 1;
        }
      }
      lab2[s] = m;
      if (m != lab[s]) s_changed = 1;   // benign race
    }
    __syncthreads();
    int ch = s_changed;
    for (int s = t; s < S; s += 256) lab[s] = lab2[s];
    __syncthreads();
    if (!ch) break;
  }

  // best member per component root (max score, min original index on tie)
  for (int s = t; s < S; s += 256) best[s] = 0ull;
  __syncthreads();
  const float* scb = scores + b * Q_;
  const int* sidx = sel_idx + b * Q_;
  for (int s = t; s < S; s += 256) {
    int orig = sidx[s];
    float sc = scb[orig];
    u64 key = ((u64)__float_as_uint(sc) << 32) | (u32)(~(u32)orig);
    atomicMax(&best[lab[s]], key);
  }
  __syncthreads();

  // roots (lab[s]==s), prefix-compact in ascending order
  int f[8]; int cnt = 0;
  #pragma unroll
  for (int e = 0; e < 8; ++e) {
    int s = t * 8 + e;
    int fl = (s < S && lab[s] == s) ? 1 : 0;
    f[e] = fl; cnt += fl;
  }
  part[t] = cnt;
  __syncthreads();
  for (int s2 = 1; s2 < 256; s2 <<= 1) {
    int v = (t >= s2) ? part[t - s2] : 0;
    __syncthreads();
    part[t] += v;
    __syncthreads();
  }
  int excl = part[t] - cnt;
  int total = part[255];
  #pragma unroll
  for (int e = 0; e < 8; ++e) {
    if (f[e]) {
      int s = t * 8 + e;
      u64 key = best[s];
      best_idx[b * Q_ + excl] = (int)(~(u32)key);
      best_sc[b * Q_ + excl] = __uint_as_float((u32)(key >> 32));
      excl++;
    }
  }
  if (t == 0) nroots[b] = total;
}

// ---------------- K5: zero entire output buffer (f32) ----------------
__global__ void k_zero(uint4* __restrict__ p, int n4) {
  int i = blockIdx.x * blockDim.x + threadIdx.x;
  if (i < n4) p[i] = make_uint4(0u, 0u, 0u, 0u);
}

// ---------------- K6: write pad_mask + seed_scores (f32) ----------------
__global__ __launch_bounds__(256)
void k_final(const float* __restrict__ best_sc, const int* __restrict__ nroots,
             float* __restrict__ out_mask, float* __restrict__ out_scores) {
  int b = blockIdx.x, t = threadIdx.x;
  int n = nroots[b];
  for (int p = t; p < n; p += 256) {
    out_mask[b * Q_ + p] = 1.0f;
    out_scores[b * Q_ + p] = best_sc[b * Q_ + p];
  }
}

// ---------------- K7: gather best signatures -> f32 output ------------
__global__ __launch_bounds__(64)
void k_gather(const float* __restrict__ sig, const int* __restrict__ best_idx,
              const int* __restrict__ nroots, float* __restrict__ out_sig) {
  int p = blockIdx.x, b = blockIdx.y;
  if (p >= nroots[b]) return;
  int row = best_idx[b * Q_ + p];
  int lane = threadIdx.x;
  float4 v = *reinterpret_cast<const float4*>(sig + ((size_t)b * Q_ + row) * C_ + lane * 4);
  *reinterpret_cast<float4*>(out_sig + ((size_t)b * Q_ + p) * C_ + lane * 4) = v;
}

extern "C" void kernel_launch(void* const* d_in, const int* in_sizes, int n_in,
                              void* d_out, int out_size, void* d_ws, size_t ws_size,
                              hipStream_t stream) {
  // defensive input-order resolution
  const float* p0 = (const float*)d_in[0];
  const float* p1 = (const float*)d_in[1];
  const float* sig;  const float* logits;
  if (in_sizes[0] == B_ * Q_ * C_) { sig = p0; logits = p1; }
  else                             { sig = p1; logits = p0; }

  float* out = (float*)d_out;
  float* out_mask   = out + OUT_SIG_ELEMS;
  float* out_scores = out + OUT_SIG_ELEMS + B_ * Q_;

  // small workspace (~0.58 MB total)
  char* ws = (char*)d_ws;
  float* scores  = (float*)ws;  ws += B_ * Q_ * 4;
  float* inv     = (float*)ws;  ws += B_ * Q_ * 4;
  int* sel_idx   = (int*)ws;    ws += B_ * Q_ * 4;
  int* best_idx  = (int*)ws;    ws += B_ * Q_ * 4;
  float* best_sc = (float*)ws;  ws += B_ * Q_ * 4;
  int* sel_cnt   = (int*)ws;    ws += 256;
  int* nroots    = (int*)ws;    ws += 256;

  // adjacency scratch lives in d_out (6.68 MB needed, 29.7 MB available);
  // consumed by k_cc, then d_out is zeroed and finalized.
  u64* adj = (u64*)d_out;

  k_scores<<<(B_ * Q_ + 255) / 256, 256, 0, stream>>>(logits, scores);
  k_inv<<<(B_ * Q_ + 3) / 4, 256, 0, stream>>>(sig, inv);
  k_compact<<<B_, 256, 0, stream>>>(scores, sel_idx, sel_cnt);

  dim3 gsim((Q_ + 63) / 64, (Q_ + 63) / 64, B_);
  k_sim<<<gsim, 256, 0, stream>>>(sig, inv, sel_idx, sel_cnt, adj);

  k_cc<<<B_, 256, 0, stream>>>(scores, sel_idx, sel_cnt, adj, best_idx, best_sc, nroots);

  int n4 = OUT_ELEMS;  // f32 bytes /16 = OUT_ELEMS*4/16; OUT_ELEMS divisible by 4
  n4 = n4 / 4;
  k_zero<<<(n4 + 255) / 256, 256, 0, stream>>>((uint4*)d_out, n4);

  k_final<<<B_, 256, 0, stream>>>(best_sc, nroots, out_mask, out_scores);

  dim3 gg(Q_, B_);
  k_gather<<<gg, 64, 0, stream>>>(sig, best_idx, nroots, out);
}

// Round 4
// 123.801 us; speedup vs baseline: 1.3036x; 1.3036x over previous
//
#include <hip/hip_runtime.h>
#include <hip/hip_bf16.h>
#include <stdint.h>

#define B_ 16
#define Q_ 1800
#define C_ 256
#define WPR 29            // u64 words per adjacency row = ceil(1800/64)
#define QPAD 1856         // WPR*64, padded compacted-row capacity
#define OUT_SIG_ELEMS (B_*Q_*C_)

typedef unsigned long long u64;
typedef unsigned int u32;
typedef __attribute__((ext_vector_type(8))) short bf16x8;   // 8 bf16 (4 VGPRs)
typedef __attribute__((ext_vector_type(4))) float f32x4;    // 4 fp32 acc

// ---------------- K1: sigmoid + select + fallback + compact (per batch) ----
__global__ __launch_bounds__(256)
void k_compact(const float* __restrict__ logits, float* __restrict__ scores,
               int* __restrict__ sel_idx, int* __restrict__ sel_cnt) {
  int b = blockIdx.x, t = threadIdx.x;
  __shared__ int part[256];
  __shared__ u64 redk[256];
  const float* lgb = logits + b * Q_;
  float* scb = scores + b * Q_;

  int f[8]; float sv[8]; int cnt = 0; u64 mk = 0;
  #pragma unroll
  for (int e = 0; e < 8; ++e) {
    int q = t * 8 + e;
    int fl = 0; float sc = 0.0f;
    if (q < Q_) {
      sc = 1.0f / (1.0f + expf(-lgb[q]));
      fl = (sc >= 0.5f) ? 1 : 0;
      u64 key = ((u64)__float_as_uint(sc) << 32) | (u32)(~(u32)q); // max score, min idx tie
      mk = (mk > key) ? mk : key;
    }
    f[e] = fl; sv[e] = sc; cnt += fl;
  }
  #pragma unroll
  for (int e = 0; e < 8; ++e) {
    int q = t * 8 + e;
    if (q < Q_) scb[q] = sv[e];
  }
  part[t] = cnt; redk[t] = mk;
  __syncthreads();
  for (int s2 = 128; s2 > 0; s2 >>= 1) {
    if (t < s2) {
      part[t] += part[t + s2];
      redk[t] = (redk[t] > redk[t + s2]) ? redk[t] : redk[t + s2];
    }
    __syncthreads();
  }
  int total_sel = part[0];
  u64 kmax = redk[0];
  __syncthreads();

  if (total_sel == 0) {                    // fallback: argmax-score query
    int fb = (int)(~(u32)kmax);
    if (fb >= t * 8 && fb < t * 8 + 8) f[fb - t * 8] = 1;
  }
  cnt = 0;
  #pragma unroll
  for (int e = 0; e < 8; ++e) cnt += f[e];
  part[t] = cnt;
  __syncthreads();
  for (int s2 = 1; s2 < 256; s2 <<= 1) {   // Hillis-Steele inclusive scan
    int v = (t >= s2) ? part[t - s2] : 0;
    __syncthreads();
    part[t] += v;
    __syncthreads();
  }
  int excl = part[t] - cnt;
  #pragma unroll
  for (int e = 0; e < 8; ++e) {
    if (f[e]) { sel_idx[b * Q_ + excl] = t * 8 + e; excl++; }
  }
  if (t == 255) sel_cnt[b] = part[255];
}

// ---------------- K2: normalize selected rows -> compacted bf16 (pad w/ 0) --
__global__ __launch_bounds__(64)
void k_prep(const float* __restrict__ sig, const int* __restrict__ sel_idx,
            const int* __restrict__ sel_cnt, unsigned short* __restrict__ nsig) {
  int p = blockIdx.x, b = blockIdx.y;
  int S = sel_cnt[b];
  int Spad = (S + 63) & ~63;
  if (p >= Spad) return;
  int lane = threadIdx.x;
  unsigned short* dst = nsig + ((size_t)b * QPAD + p) * C_;
  if (p >= S) {                             // zero-pad row
    *reinterpret_cast<uint2*>(dst + lane * 4) = make_uint2(0u, 0u);
    return;
  }
  int row = sel_idx[b * Q_ + p];
  const float* src = sig + ((size_t)b * Q_ + row) * C_;
  float4 v = *reinterpret_cast<const float4*>(src + lane * 4);
  float ss = v.x * v.x + v.y * v.y + v.z * v.z + v.w * v.w;
  #pragma unroll
  for (int m = 32; m; m >>= 1) ss += __shfl_xor(ss, m, 64);
  float inv = 1.0f / fmaxf(sqrtf(ss), 1e-12f);
  __hip_bfloat16 h0 = __float2bfloat16(v.x * inv);
  __hip_bfloat16 h1 = __float2bfloat16(v.y * inv);
  __hip_bfloat16 h2 = __float2bfloat16(v.z * inv);
  __hip_bfloat16 h3 = __float2bfloat16(v.w * inv);
  unsigned short u0, u1, u2, u3;
  __builtin_memcpy(&u0, &h0, 2); __builtin_memcpy(&u1, &h1, 2);
  __builtin_memcpy(&u2, &h2, 2); __builtin_memcpy(&u3, &h3, 2);
  uint2 wv;
  wv.x = (u32)u0 | ((u32)u1 << 16);
  wv.y = (u32)u2 | ((u32)u3 << 16);
  *reinterpret_cast<uint2*>(dst + lane * 4) = wv;
}

// ---------------- K3: MFMA cosine-sim 64x64 tiles -> adjacency bits --------
// 4 waves/block; wave w computes rows [w*16,w*16+16) x 64 cols.
// A-frag: lane l holds A[l&15][(l>>4)*8 + j]; B-frag: lane l holds B[(l>>4)*8+j][l&15]
// (B[k][col] = nsig[j0+col][k]); D: col=lane&15, row=(lane>>4)*4+reg  [m89-verified]
__global__ __launch_bounds__(256)
void k_sim(const unsigned short* __restrict__ nsig, const int* __restrict__ sel_cnt,
           u64* __restrict__ adj) {
  int b = blockIdx.z;
  int S = sel_cnt[b];
  int i0 = blockIdx.y * 64, j0 = blockIdx.x * 64;
  if (i0 >= S || j0 >= S) return;

  __shared__ u64 adjtile[64];
  int t = threadIdx.x;
  int wv = t >> 6, lane = t & 63;
  int lr = lane & 15, lg = lane >> 4;

  const unsigned short* base = nsig + (size_t)b * QPAD * C_;
  const unsigned short* ap = base + (size_t)(i0 + wv * 16 + lr) * C_ + lg * 8;
  const unsigned short* bp = base + (size_t)(j0 + lr) * C_ + lg * 8;

  f32x4 acc0 = {0.f,0.f,0.f,0.f}, acc1 = {0.f,0.f,0.f,0.f};
  f32x4 acc2 = {0.f,0.f,0.f,0.f}, acc3 = {0.f,0.f,0.f,0.f};
  #pragma unroll
  for (int ks = 0; ks < 8; ++ks) {
    bf16x8 a  = *reinterpret_cast<const bf16x8*>(ap + ks * 32);
    bf16x8 b0 = *reinterpret_cast<const bf16x8*>(bp + 0 * 16 * C_ + ks * 32);
    bf16x8 b1 = *reinterpret_cast<const bf16x8*>(bp + 1 * 16 * C_ + ks * 32);
    bf16x8 b2 = *reinterpret_cast<const bf16x8*>(bp + 2 * 16 * C_ + ks * 32);
    bf16x8 b3 = *reinterpret_cast<const bf16x8*>(bp + 3 * 16 * C_ + ks * 32);
    acc0 = __builtin_amdgcn_mfma_f32_16x16x32_bf16(a, b0, acc0, 0, 0, 0);
    acc1 = __builtin_amdgcn_mfma_f32_16x16x32_bf16(a, b1, acc1, 0, 0, 0);
    acc2 = __builtin_amdgcn_mfma_f32_16x16x32_bf16(a, b2, acc2, 0, 0, 0);
    acc3 = __builtin_amdgcn_mfma_f32_16x16x32_bf16(a, b3, acc3, 0, 0, 0);
  }

  if (t < 64) adjtile[t] = 0ull;
  __syncthreads();
  int rbase = wv * 16 + lg * 4;
  #pragma unroll
  for (int j = 0; j < 4; ++j) {
    u64 bits = 0ull;
    if (acc0[j] >= 0.8f) bits |= 1ull << (0  + lr);
    if (acc1[j] >= 0.8f) bits |= 1ull << (16 + lr);
    if (acc2[j] >= 0.8f) bits |= 1ull << (32 + lr);
    if (acc3[j] >= 0.8f) bits |= 1ull << (48 + lr);
    if (bits) atomicOr(&adjtile[rbase + j], bits);
  }
  __syncthreads();
  if (t < 64) {
    int gi = i0 + t;
    if (gi < S) adj[((size_t)b * Q_ + gi) * WPR + blockIdx.x] = adjtile[t];
  }
}

// ---------------- K4: CC label propagation + best-per-component + compact --
__global__ __launch_bounds__(256)
void k_cc(const float* __restrict__ scores, const int* __restrict__ sel_idx,
          const int* __restrict__ sel_cnt, const u64* __restrict__ adj,
          int* __restrict__ best_idx, float* __restrict__ best_sc,
          int* __restrict__ nroots) {
  int b = blockIdx.x, t = threadIdx.x;
  __shared__ int lab[Q_];
  __shared__ int lab2[Q_];
  __shared__ u64 best[Q_];
  __shared__ int part[256];
  __shared__ int s_changed;

  int S = sel_cnt[b];
  int nw = (S + 63) >> 6;
  const u64* arow0 = adj + (size_t)b * Q_ * WPR;

  for (int s = t; s < S; s += 256) lab[s] = s;
  __syncthreads();

  for (int iter = 0; iter < Q_ + 2; ++iter) {
    if (t == 0) s_changed = 0;
    __syncthreads();
    for (int s = t; s < S; s += 256) {
      int m = lab[s];
      const u64* row = arow0 + (size_t)s * WPR;
      for (int w = 0; w < nw; ++w) {
        u64 msk = row[w];
        while (msk) {
          int j = (w << 6) + __builtin_ctzll(msk);
          int lj = lab[j];
          m = (lj < m) ? lj : m;
          msk &= msk - 1;
        }
      }
      lab2[s] = m;
      if (m != lab[s]) s_changed = 1;   // benign race
    }
    __syncthreads();
    int ch = s_changed;
    for (int s = t; s < S; s += 256) lab[s] = lab2[s];
    __syncthreads();
    if (!ch) break;
  }

  // best member per component root (max score, min original index on tie)
  for (int s = t; s < S; s += 256) best[s] = 0ull;
  __syncthreads();
  const float* scb = scores + b * Q_;
  const int* sidx = sel_idx + b * Q_;
  for (int s = t; s < S; s += 256) {
    int orig = sidx[s];
    float sc = scb[orig];
    u64 key = ((u64)__float_as_uint(sc) << 32) | (u32)(~(u32)orig);
    atomicMax(&best[lab[s]], key);
  }
  __syncthreads();

  // roots (lab[s]==s), prefix-compact in ascending order
  int f[8]; int cnt = 0;
  #pragma unroll
  for (int e = 0; e < 8; ++e) {
    int s = t * 8 + e;
    int fl = (s < S && lab[s] == s) ? 1 : 0;
    f[e] = fl; cnt += fl;
  }
  part[t] = cnt;
  __syncthreads();
  for (int s2 = 1; s2 < 256; s2 <<= 1) {
    int v = (t >= s2) ? part[t - s2] : 0;
    __syncthreads();
    part[t] += v;
    __syncthreads();
  }
  int excl = part[t] - cnt;
  int total = part[255];
  #pragma unroll
  for (int e = 0; e < 8; ++e) {
    if (f[e]) {
      int s = t * 8 + e;
      u64 key = best[s];
      best_idx[b * Q_ + excl] = (int)(~(u32)key);
      best_sc[b * Q_ + excl] = __uint_as_float((u32)(key >> 32));
      excl++;
    }
  }
  if (t == 0) nroots[b] = total;
}

// ---------------- K5: write ALL outputs (sig rows, mask, scores) -----------
// Full coverage of d_out every launch (also wipes the adj/nsig scratch).
__global__ __launch_bounds__(64)
void k_gather(const float* __restrict__ sig, const int* __restrict__ best_idx,
              const float* __restrict__ best_sc, const int* __restrict__ nroots,
              float* __restrict__ out_sig, float* __restrict__ out_mask,
              float* __restrict__ out_scores) {
  int p = blockIdx.x, b = blockIdx.y;
  int lane = threadIdx.x;
  int n = nroots[b];
  float* orow = out_sig + ((size_t)b * Q_ + p) * C_;
  if (p < n) {
    int row = best_idx[b * Q_ + p];
    float4 v = *reinterpret_cast<const float4*>(sig + ((size_t)b * Q_ + row) * C_ + lane * 4);
    *reinterpret_cast<float4*>(orow + lane * 4) = v;
    if (lane == 0) {
      out_mask[b * Q_ + p] = 1.0f;
      out_scores[b * Q_ + p] = best_sc[b * Q_ + p];
    }
  } else {
    *reinterpret_cast<float4*>(orow + lane * 4) = make_float4(0.f, 0.f, 0.f, 0.f);
    if (lane == 0) {
      out_mask[b * Q_ + p] = 0.0f;
      out_scores[b * Q_ + p] = 0.0f;
    }
  }
}

extern "C" void kernel_launch(void* const* d_in, const int* in_sizes, int n_in,
                              void* d_out, int out_size, void* d_ws, size_t ws_size,
                              hipStream_t stream) {
  // defensive input-order resolution
  const float* p0 = (const float*)d_in[0];
  const float* p1 = (const float*)d_in[1];
  const float* sig;  const float* logits;
  if (in_sizes[0] == B_ * Q_ * C_) { sig = p0; logits = p1; }
  else                             { sig = p1; logits = p0; }

  float* out = (float*)d_out;
  float* out_mask   = out + OUT_SIG_ELEMS;
  float* out_scores = out + OUT_SIG_ELEMS + B_ * Q_;

  // small workspace (~0.5 MB)
  char* ws = (char*)d_ws;
  float* scores  = (float*)ws;  ws += B_ * Q_ * 4;
  int* sel_idx   = (int*)ws;    ws += B_ * Q_ * 4;
  int* best_idx  = (int*)ws;    ws += B_ * Q_ * 4;
  float* best_sc = (float*)ws;  ws += B_ * Q_ * 4;
  int* sel_cnt   = (int*)ws;    ws += 256;
  int* nroots    = (int*)ws;    ws += 256;

  // scratch inside d_out (29.7 MB): adj bits [0, 6.68 MB), bf16 nsig at +8 MB
  // (15.2 MB). Both fully rewritten before use each launch; k_gather then
  // overwrites all of d_out with final outputs.
  u64* adj = (u64*)d_out;
  unsigned short* nsig = (unsigned short*)((char*)d_out + (size_t)(8u << 20));

  k_compact<<<B_, 256, 0, stream>>>(logits, scores, sel_idx, sel_cnt);

  dim3 gp(Q_, B_);
  k_prep<<<gp, 64, 0, stream>>>(sig, sel_idx, sel_cnt, nsig);

  dim3 gsim(WPR, WPR, B_);
  k_sim<<<gsim, 256, 0, stream>>>(nsig, sel_cnt, adj);

  k_cc<<<B_, 256, 0, stream>>>(scores, sel_idx, sel_cnt, adj, best_idx, best_sc, nroots);

  dim3 gg(Q_, B_);
  k_gather<<<gg, 64, 0, stream>>>(sig, best_idx, best_sc, nroots,
                                  out, out_mask, out_scores);
}

// Round 5
// 118.766 us; speedup vs baseline: 1.3589x; 1.0424x over previous
//
#include <hip/hip_runtime.h>
#include <hip/hip_bf16.h>
#include <stdint.h>

#define B_ 16
#define Q_ 1800
#define C_ 256
#define WPR 29            // u64 words per adjacency row = ceil(1800/64)
#define QPAD 1856         // WPR*64, padded compacted-row capacity
#define OUT_SIG_ELEMS (B_*Q_*C_)

typedef unsigned long long u64;
typedef unsigned int u32;
typedef __attribute__((ext_vector_type(8))) short bf16x8;   // 8 bf16 (4 VGPRs)
typedef __attribute__((ext_vector_type(4))) float f32x4;    // 4 fp32 acc

// ---------------- K1: sigmoid + select + fallback + compact (per batch) ----
__global__ __launch_bounds__(256)
void k_compact(const float* __restrict__ logits, float* __restrict__ scores,
               int* __restrict__ sel_idx, int* __restrict__ sel_cnt) {
  int b = blockIdx.x, t = threadIdx.x;
  __shared__ int part[256];
  __shared__ u64 redk[256];
  const float* lgb = logits + b * Q_;
  float* scb = scores + b * Q_;

  int f[8]; float sv[8]; int cnt = 0; u64 mk = 0;
  #pragma unroll
  for (int e = 0; e < 8; ++e) {
    int q = t * 8 + e;
    int fl = 0; float sc = 0.0f;
    if (q < Q_) {
      sc = 1.0f / (1.0f + expf(-lgb[q]));
      fl = (sc >= 0.5f) ? 1 : 0;
      u64 key = ((u64)__float_as_uint(sc) << 32) | (u32)(~(u32)q); // max score, min idx tie
      mk = (mk > key) ? mk : key;
    }
    f[e] = fl; sv[e] = sc; cnt += fl;
  }
  #pragma unroll
  for (int e = 0; e < 8; ++e) {
    int q = t * 8 + e;
    if (q < Q_) scb[q] = sv[e];
  }
  part[t] = cnt; redk[t] = mk;
  __syncthreads();
  for (int s2 = 128; s2 > 0; s2 >>= 1) {
    if (t < s2) {
      part[t] += part[t + s2];
      redk[t] = (redk[t] > redk[t + s2]) ? redk[t] : redk[t + s2];
    }
    __syncthreads();
  }
  int total_sel = part[0];
  u64 kmax = redk[0];
  __syncthreads();

  if (total_sel == 0) {                    // fallback: argmax-score query
    int fb = (int)(~(u32)kmax);
    if (fb >= t * 8 && fb < t * 8 + 8) f[fb - t * 8] = 1;
  }
  cnt = 0;
  #pragma unroll
  for (int e = 0; e < 8; ++e) cnt += f[e];
  part[t] = cnt;
  __syncthreads();
  for (int s2 = 1; s2 < 256; s2 <<= 1) {   // Hillis-Steele inclusive scan
    int v = (t >= s2) ? part[t - s2] : 0;
    __syncthreads();
    part[t] += v;
    __syncthreads();
  }
  int excl = part[t] - cnt;
  #pragma unroll
  for (int e = 0; e < 8; ++e) {
    if (f[e]) { sel_idx[b * Q_ + excl] = t * 8 + e; excl++; }
  }
  if (t == 255) sel_cnt[b] = part[255];
}

// ---------------- K2: normalize selected rows -> compacted bf16 (pad w/ 0) --
// 4 rows per 256-thread block; covers ALL QPAD rows (pad rows up to Spad zeroed).
__global__ __launch_bounds__(256)
void k_prep(const float* __restrict__ sig, const int* __restrict__ sel_idx,
            const int* __restrict__ sel_cnt, unsigned short* __restrict__ nsig) {
  int b = blockIdx.y;
  int p = blockIdx.x * 4 + (threadIdx.x >> 6);
  int lane = threadIdx.x & 63;
  int S = sel_cnt[b];
  int Spad = (S + 63) & ~63;
  if (p >= Spad) return;
  unsigned short* dst = nsig + ((size_t)b * QPAD + p) * C_;
  if (p >= S) {                             // zero-pad row
    *reinterpret_cast<uint2*>(dst + lane * 4) = make_uint2(0u, 0u);
    return;
  }
  int row = sel_idx[b * Q_ + p];
  const float* src = sig + ((size_t)b * Q_ + row) * C_;
  float4 v = *reinterpret_cast<const float4*>(src + lane * 4);
  float ss = v.x * v.x + v.y * v.y + v.z * v.z + v.w * v.w;
  #pragma unroll
  for (int m = 32; m; m >>= 1) ss += __shfl_xor(ss, m, 64);
  float inv = 1.0f / fmaxf(sqrtf(ss), 1e-12f);
  __hip_bfloat16 h0 = __float2bfloat16(v.x * inv);
  __hip_bfloat16 h1 = __float2bfloat16(v.y * inv);
  __hip_bfloat16 h2 = __float2bfloat16(v.z * inv);
  __hip_bfloat16 h3 = __float2bfloat16(v.w * inv);
  unsigned short u0, u1, u2, u3;
  __builtin_memcpy(&u0, &h0, 2); __builtin_memcpy(&u1, &h1, 2);
  __builtin_memcpy(&u2, &h2, 2); __builtin_memcpy(&u3, &h3, 2);
  uint2 wv;
  wv.x = (u32)u0 | ((u32)u1 << 16);
  wv.y = (u32)u2 | ((u32)u3 << 16);
  *reinterpret_cast<uint2*>(dst + lane * 4) = wv;
}

// ---------------- K3: MFMA cosine-sim 64x64 tiles -> adjacency bits --------
// 1-D grid, batch = lin & 15 -> XCD = lin % 8 = batch % 8 (round-robin pin):
// each batch's ~0.5 MB working set stays in one XCD's private L2.
// 4 waves/block; wave w computes rows [w*16,w*16+16) x 64 cols.
// A-frag: lane l holds A[l&15][(l>>4)*8 + j]; B-frag: lane l holds B[(l>>4)*8+j][l&15]
// D: col=lane&15, row=(lane>>4)*4+reg  [m89-verified]
__global__ __launch_bounds__(256)
void k_sim(const unsigned short* __restrict__ nsig, const int* __restrict__ sel_cnt,
           u64* __restrict__ adj) {
  int lin = blockIdx.x;
  int b = lin & 15;
  int tile = lin >> 4;
  int ti = tile / WPR, tj = tile - ti * WPR;
  int S = sel_cnt[b];
  int i0 = ti * 64, j0 = tj * 64;
  if (i0 >= S || j0 >= S) return;

  __shared__ u64 adjtile[64];
  int t = threadIdx.x;
  int wv = t >> 6, lane = t & 63;
  int lr = lane & 15, lg = lane >> 4;

  const unsigned short* base = nsig + (size_t)b * QPAD * C_;
  const unsigned short* ap = base + (size_t)(i0 + wv * 16 + lr) * C_ + lg * 8;
  const unsigned short* bp = base + (size_t)(j0 + lr) * C_ + lg * 8;

  // preload all 8 A-fragments (one row region, 32 VGPRs)
  bf16x8 a[8];
  #pragma unroll
  for (int ks = 0; ks < 8; ++ks) a[ks] = *reinterpret_cast<const bf16x8*>(ap + ks * 32);

  f32x4 acc0 = {0.f,0.f,0.f,0.f}, acc1 = {0.f,0.f,0.f,0.f};
  f32x4 acc2 = {0.f,0.f,0.f,0.f}, acc3 = {0.f,0.f,0.f,0.f};

  // double-buffered B-fragments: loads for ks+1 issue under MFMAs of ks
  bf16x8 b0 = *reinterpret_cast<const bf16x8*>(bp + 0 * 16 * C_);
  bf16x8 b1 = *reinterpret_cast<const bf16x8*>(bp + 1 * 16 * C_);
  bf16x8 b2 = *reinterpret_cast<const bf16x8*>(bp + 2 * 16 * C_);
  bf16x8 b3 = *reinterpret_cast<const bf16x8*>(bp + 3 * 16 * C_);
  #pragma unroll
  for (int ks = 0; ks < 8; ++ks) {
    bf16x8 n0, n1, n2, n3;
    if (ks < 7) {
      n0 = *reinterpret_cast<const bf16x8*>(bp + 0 * 16 * C_ + (ks + 1) * 32);
      n1 = *reinterpret_cast<const bf16x8*>(bp + 1 * 16 * C_ + (ks + 1) * 32);
      n2 = *reinterpret_cast<const bf16x8*>(bp + 2 * 16 * C_ + (ks + 1) * 32);
      n3 = *reinterpret_cast<const bf16x8*>(bp + 3 * 16 * C_ + (ks + 1) * 32);
    }
    acc0 = __builtin_amdgcn_mfma_f32_16x16x32_bf16(a[ks], b0, acc0, 0, 0, 0);
    acc1 = __builtin_amdgcn_mfma_f32_16x16x32_bf16(a[ks], b1, acc1, 0, 0, 0);
    acc2 = __builtin_amdgcn_mfma_f32_16x16x32_bf16(a[ks], b2, acc2, 0, 0, 0);
    acc3 = __builtin_amdgcn_mfma_f32_16x16x32_bf16(a[ks], b3, acc3, 0, 0, 0);
    b0 = n0; b1 = n1; b2 = n2; b3 = n3;
  }

  if (t < 64) adjtile[t] = 0ull;
  __syncthreads();
  int rbase = wv * 16 + lg * 4;
  #pragma unroll
  for (int j = 0; j < 4; ++j) {
    u64 bits = 0ull;
    if (acc0[j] >= 0.8f) bits |= 1ull << (0  + lr);
    if (acc1[j] >= 0.8f) bits |= 1ull << (16 + lr);
    if (acc2[j] >= 0.8f) bits |= 1ull << (32 + lr);
    if (acc3[j] >= 0.8f) bits |= 1ull << (48 + lr);
    if (bits) atomicOr(&adjtile[rbase + j], bits);
  }
  __syncthreads();
  if (t < 64) {
    int gi = i0 + t;
    if (gi < S) adj[((size_t)b * Q_ + gi) * WPR + tj] = adjtile[t];
  }
}

// ---------------- K4: CC label propagation + best-per-component + compact --
__global__ __launch_bounds__(256)
void k_cc(const float* __restrict__ scores, const int* __restrict__ sel_idx,
          const int* __restrict__ sel_cnt, const u64* __restrict__ adj,
          int* __restrict__ best_idx, float* __restrict__ best_sc,
          int* __restrict__ nroots) {
  int b = blockIdx.x, t = threadIdx.x;
  __shared__ int lab[Q_];
  __shared__ int lab2[Q_];
  __shared__ u64 best[Q_];
  __shared__ int part[256];
  __shared__ int s_changed;

  int S = sel_cnt[b];
  int nw = (S + 63) >> 6;
  const u64* arow0 = adj + (size_t)b * Q_ * WPR;

  for (int s = t; s < S; s += 256) lab[s] = s;
  __syncthreads();

  for (int iter = 0; iter < Q_ + 2; ++iter) {
    if (t == 0) s_changed = 0;
    __syncthreads();
    for (int s = t; s < S; s += 256) {
      int m = lab[s];
      const u64* row = arow0 + (size_t)s * WPR;
      for (int w = 0; w < nw; ++w) {
        u64 msk = row[w];
        while (msk) {
          int j = (w << 6) + __builtin_ctzll(msk);
          int lj = lab[j];
          m = (lj < m) ? lj : m;
          msk &= msk - 1;
        }
      }
      lab2[s] = m;
      if (m != lab[s]) s_changed = 1;   // benign race
    }
    __syncthreads();
    int ch = s_changed;
    for (int s = t; s < S; s += 256) lab[s] = lab2[s];
    __syncthreads();
    if (!ch) break;
  }

  // best member per component root (max score, min original index on tie)
  for (int s = t; s < S; s += 256) best[s] = 0ull;
  __syncthreads();
  const float* scb = scores + b * Q_;
  const int* sidx = sel_idx + b * Q_;
  for (int s = t; s < S; s += 256) {
    int orig = sidx[s];
    float sc = scb[orig];
    u64 key = ((u64)__float_as_uint(sc) << 32) | (u32)(~(u32)orig);
    atomicMax(&best[lab[s]], key);
  }
  __syncthreads();

  // roots (lab[s]==s), prefix-compact in ascending order
  int f[8]; int cnt = 0;
  #pragma unroll
  for (int e = 0; e < 8; ++e) {
    int s = t * 8 + e;
    int fl = (s < S && lab[s] == s) ? 1 : 0;
    f[e] = fl; cnt += fl;
  }
  part[t] = cnt;
  __syncthreads();
  for (int s2 = 1; s2 < 256; s2 <<= 1) {
    int v = (t >= s2) ? part[t - s2] : 0;
    __syncthreads();
    part[t] += v;
    __syncthreads();
  }
  int excl = part[t] - cnt;
  int total = part[255];
  #pragma unroll
  for (int e = 0; e < 8; ++e) {
    if (f[e]) {
      int s = t * 8 + e;
      u64 key = best[s];
      best_idx[b * Q_ + excl] = (int)(~(u32)key);
      best_sc[b * Q_ + excl] = __uint_as_float((u32)(key >> 32));
      excl++;
    }
  }
  if (t == 0) nroots[b] = total;
}

// ---------------- K5: write ALL outputs (sig rows, mask, scores) -----------
// Full coverage of d_out every launch (also wipes the adj/nsig scratch).
// 4 rows per 256-thread block.
__global__ __launch_bounds__(256)
void k_gather(const float* __restrict__ sig, const int* __restrict__ best_idx,
              const float* __restrict__ best_sc, const int* __restrict__ nroots,
              float* __restrict__ out_sig, float* __restrict__ out_mask,
              float* __restrict__ out_scores) {
  int b = blockIdx.y;
  int p = blockIdx.x * 4 + (threadIdx.x >> 6);
  int lane = threadIdx.x & 63;
  if (p >= Q_) return;
  int n = nroots[b];
  float* orow = out_sig + ((size_t)b * Q_ + p) * C_;
  if (p < n) {
    int row = best_idx[b * Q_ + p];
    float4 v = *reinterpret_cast<const float4*>(sig + ((size_t)b * Q_ + row) * C_ + lane * 4);
    *reinterpret_cast<float4*>(orow + lane * 4) = v;
    if (lane == 0) {
      out_mask[b * Q_ + p] = 1.0f;
      out_scores[b * Q_ + p] = best_sc[b * Q_ + p];
    }
  } else {
    *reinterpret_cast<float4*>(orow + lane * 4) = make_float4(0.f, 0.f, 0.f, 0.f);
    if (lane == 0) {
      out_mask[b * Q_ + p] = 0.0f;
      out_scores[b * Q_ + p] = 0.0f;
    }
  }
}

extern "C" void kernel_launch(void* const* d_in, const int* in_sizes, int n_in,
                              void* d_out, int out_size, void* d_ws, size_t ws_size,
                              hipStream_t stream) {
  // defensive input-order resolution
  const float* p0 = (const float*)d_in[0];
  const float* p1 = (const float*)d_in[1];
  const float* sig;  const float* logits;
  if (in_sizes[0] == B_ * Q_ * C_) { sig = p0; logits = p1; }
  else                             { sig = p1; logits = p0; }

  float* out = (float*)d_out;
  float* out_mask   = out + OUT_SIG_ELEMS;
  float* out_scores = out + OUT_SIG_ELEMS + B_ * Q_;

  // small workspace (~0.5 MB)
  char* ws = (char*)d_ws;
  float* scores  = (float*)ws;  ws += B_ * Q_ * 4;
  int* sel_idx   = (int*)ws;    ws += B_ * Q_ * 4;
  int* best_idx  = (int*)ws;    ws += B_ * Q_ * 4;
  float* best_sc = (float*)ws;  ws += B_ * Q_ * 4;
  int* sel_cnt   = (int*)ws;    ws += 256;
  int* nroots    = (int*)ws;    ws += 256;

  // scratch inside d_out (29.7 MB): adj bits [0, 6.68 MB), bf16 nsig at +8 MB
  // (15.2 MB). Both fully rewritten before use each launch; k_gather then
  // overwrites all of d_out with final outputs.
  u64* adj = (u64*)d_out;
  unsigned short* nsig = (unsigned short*)((char*)d_out + (size_t)(8u << 20));

  k_compact<<<B_, 256, 0, stream>>>(logits, scores, sel_idx, sel_cnt);

  dim3 gp(QPAD / 4, B_);
  k_prep<<<gp, 256, 0, stream>>>(sig, sel_idx, sel_cnt, nsig);

  // 1-D grid: batch = lin & 15 pins each batch to XCD (lin % 8 == batch % 8)
  k_sim<<<B_ * WPR * WPR, 256, 0, stream>>>(nsig, sel_cnt, adj);

  k_cc<<<B_, 256, 0, stream>>>(scores, sel_idx, sel_cnt, adj, best_idx, best_sc, nroots);

  dim3 gg(Q_ / 4, B_);
  k_gather<<<gg, 256, 0, stream>>>(sig, best_idx, best_sc, nroots,
                                   out, out_mask, out_scores);
}

// Round 6
// 83.094 us; speedup vs baseline: 1.9423x; 1.4293x over previous
//
#include <hip/hip_runtime.h>
#include <hip/hip_bf16.h>
#include <stdint.h>

#define B_ 16
#define Q_ 1800
#define C_ 256
#define WPR 29            // u64 words per adjacency row = ceil(1800/64)
#define QPAD 1856         // WPR*64, padded compacted-row capacity
#define TB_ 15            // 128-wide tiles per dim: 15*128 = 1920 >= QPAD
#define OUT_SIG_ELEMS (B_*Q_*C_)

typedef unsigned long long u64;
typedef unsigned int u32;
typedef __attribute__((ext_vector_type(8))) short bf16x8;   // 8 bf16 (4 VGPRs)
typedef __attribute__((ext_vector_type(4))) float f32x4;    // 4 fp32 acc

// ---------------- K1: sigmoid + select + fallback + compact (per batch) ----
__global__ __launch_bounds__(256)
void k_compact(const float* __restrict__ logits, float* __restrict__ scores,
               int* __restrict__ sel_idx, int* __restrict__ sel_cnt) {
  int b = blockIdx.x, t = threadIdx.x;
  __shared__ int part[256];
  __shared__ u64 redk[256];
  const float* lgb = logits + b * Q_;
  float* scb = scores + b * Q_;

  int f[8]; float sv[8]; int cnt = 0; u64 mk = 0;
  #pragma unroll
  for (int e = 0; e < 8; ++e) {
    int q = t * 8 + e;
    int fl = 0; float sc = 0.0f;
    if (q < Q_) {
      sc = 1.0f / (1.0f + expf(-lgb[q]));
      fl = (sc >= 0.5f) ? 1 : 0;
      u64 key = ((u64)__float_as_uint(sc) << 32) | (u32)(~(u32)q); // max score, min idx tie
      mk = (mk > key) ? mk : key;
    }
    f[e] = fl; sv[e] = sc; cnt += fl;
  }
  #pragma unroll
  for (int e = 0; e < 8; ++e) {
    int q = t * 8 + e;
    if (q < Q_) scb[q] = sv[e];
  }
  part[t] = cnt; redk[t] = mk;
  __syncthreads();
  for (int s2 = 128; s2 > 0; s2 >>= 1) {
    if (t < s2) {
      part[t] += part[t + s2];
      redk[t] = (redk[t] > redk[t + s2]) ? redk[t] : redk[t + s2];
    }
    __syncthreads();
  }
  int total_sel = part[0];
  u64 kmax = redk[0];
  __syncthreads();

  if (total_sel == 0) {                    // fallback: argmax-score query
    int fb = (int)(~(u32)kmax);
    if (fb >= t * 8 && fb < t * 8 + 8) f[fb - t * 8] = 1;
  }
  cnt = 0;
  #pragma unroll
  for (int e = 0; e < 8; ++e) cnt += f[e];
  part[t] = cnt;
  __syncthreads();
  for (int s2 = 1; s2 < 256; s2 <<= 1) {   // Hillis-Steele inclusive scan
    int v = (t >= s2) ? part[t - s2] : 0;
    __syncthreads();
    part[t] += v;
    __syncthreads();
  }
  int excl = part[t] - cnt;
  #pragma unroll
  for (int e = 0; e < 8; ++e) {
    if (f[e]) { sel_idx[b * Q_ + excl] = t * 8 + e; excl++; }
  }
  if (t == 255) sel_cnt[b] = part[255];
}

// ---------------- K2: normalize selected rows -> compacted bf16 (pad w/ 0) --
__global__ __launch_bounds__(256)
void k_prep(const float* __restrict__ sig, const int* __restrict__ sel_idx,
            const int* __restrict__ sel_cnt, unsigned short* __restrict__ nsig) {
  int b = blockIdx.y;
  int p = blockIdx.x * 4 + (threadIdx.x >> 6);
  int lane = threadIdx.x & 63;
  int S = sel_cnt[b];
  int Spad = (S + 63) & ~63;
  if (p >= Spad) return;
  unsigned short* dst = nsig + ((size_t)b * QPAD + p) * C_;
  if (p >= S) {                             // zero-pad row
    *reinterpret_cast<uint2*>(dst + lane * 4) = make_uint2(0u, 0u);
    return;
  }
  int row = sel_idx[b * Q_ + p];
  const float* src = sig + ((size_t)b * Q_ + row) * C_;
  float4 v = *reinterpret_cast<const float4*>(src + lane * 4);
  float ss = v.x * v.x + v.y * v.y + v.z * v.z + v.w * v.w;
  #pragma unroll
  for (int m = 32; m; m >>= 1) ss += __shfl_xor(ss, m, 64);
  float inv = 1.0f / fmaxf(sqrtf(ss), 1e-12f);
  __hip_bfloat16 h0 = __float2bfloat16(v.x * inv);
  __hip_bfloat16 h1 = __float2bfloat16(v.y * inv);
  __hip_bfloat16 h2 = __float2bfloat16(v.z * inv);
  __hip_bfloat16 h3 = __float2bfloat16(v.w * inv);
  unsigned short u0, u1, u2, u3;
  __builtin_memcpy(&u0, &h0, 2); __builtin_memcpy(&u1, &h1, 2);
  __builtin_memcpy(&u2, &h2, 2); __builtin_memcpy(&u3, &h3, 2);
  uint2 wv;
  wv.x = (u32)u0 | ((u32)u1 << 16);
  wv.y = (u32)u2 | ((u32)u3 << 16);
  *reinterpret_cast<uint2*>(dst + lane * 4) = wv;
}

// ---------------- K3: MFMA cosine-sim, 64x64 PER WAVE -> adjacency bits ----
// 1-D grid, batch = lin & 15 -> XCD pin (lin%8 == b%8): per-batch working set
// stays in one XCD's L2. Block = 4 waves covering a 128x128 region; wave w
// owns the 64x64 tile at (+64*(w>>1), +64*(w&1)). No __syncthreads: each wave
// uses a private adjtile strip (wave-ordered DS ops).
// Layouts (validated bit-exact in rounds 4/5):
//   A-frag lane l: row=l&15, k-slice=(l>>4)*8;  B-frag lane l: col=l&15,
//   k-slice=(l>>4)*8;  D: col=lane&15, row=(lane>>4)*4+reg.
// Pipelining: ping-pong frag buffers + sched_barrier(0) pins 8 prefetch
// loads BEFORE each MFMA group so ~8 loads stay in flight (counted vmcnt).
__global__ __launch_bounds__(256)
void k_sim(const unsigned short* __restrict__ nsig, const int* __restrict__ sel_cnt,
           u64* __restrict__ adj) {
  int lin = blockIdx.x;
  int b = lin & 15;
  int tile = lin >> 4;
  int tib = tile / TB_, tjb = tile - tib * TB_;
  int S = sel_cnt[b];

  int t = threadIdx.x;
  int wv = t >> 6, lane = t & 63;
  int lr = lane & 15, lg = lane >> 4;

  int i1 = tib * 128 + (wv >> 1) * 64;
  int j1 = tjb * 128 + (wv & 1) * 64;
  if (i1 >= S || j1 >= S) return;

  __shared__ u64 adjtile[4][64];

  const unsigned short* base = nsig + (size_t)b * QPAD * C_;
  const unsigned short* apA[4];
  const unsigned short* apB[4];
  #pragma unroll
  for (int rs = 0; rs < 4; ++rs) {
    apA[rs] = base + (size_t)(i1 + rs * 16 + lr) * C_ + lg * 8;
    apB[rs] = base + (size_t)(j1 + rs * 16 + lr) * C_ + lg * 8;
  }

  f32x4 acc[4][4];
  #pragma unroll
  for (int rs = 0; rs < 4; ++rs)
    #pragma unroll
    for (int cg = 0; cg < 4; ++cg) acc[rs][cg] = (f32x4){0.f, 0.f, 0.f, 0.f};

  bf16x8 abuf[2][4], bbuf[2][4];
  #pragma unroll
  for (int rs = 0; rs < 4; ++rs) {
    abuf[0][rs] = *reinterpret_cast<const bf16x8*>(apA[rs]);
    bbuf[0][rs] = *reinterpret_cast<const bf16x8*>(apB[rs]);
  }
  #pragma unroll
  for (int ks = 0; ks < 8; ++ks) {
    const int cur = ks & 1, nxt = cur ^ 1;
    if (ks < 7) {
      #pragma unroll
      for (int rs = 0; rs < 4; ++rs) {
        abuf[nxt][rs] = *reinterpret_cast<const bf16x8*>(apA[rs] + (ks + 1) * 32);
        bbuf[nxt][rs] = *reinterpret_cast<const bf16x8*>(apB[rs] + (ks + 1) * 32);
      }
    }
    __builtin_amdgcn_sched_barrier(0);   // loads must issue before these MFMAs
    #pragma unroll
    for (int rs = 0; rs < 4; ++rs)
      #pragma unroll
      for (int cg = 0; cg < 4; ++cg)
        acc[rs][cg] = __builtin_amdgcn_mfma_f32_16x16x32_bf16(
            abuf[cur][rs], bbuf[cur][cg], acc[rs][cg], 0, 0, 0);
  }

  adjtile[wv][lane] = 0ull;              // wave-private strip, wave-ordered
  #pragma unroll
  for (int rs = 0; rs < 4; ++rs) {
    #pragma unroll
    for (int j = 0; j < 4; ++j) {
      u64 bits = 0ull;
      if (acc[rs][0][j] >= 0.8f) bits |= 1ull << (0  + lr);
      if (acc[rs][1][j] >= 0.8f) bits |= 1ull << (16 + lr);
      if (acc[rs][2][j] >= 0.8f) bits |= 1ull << (32 + lr);
      if (acc[rs][3][j] >= 0.8f) bits |= 1ull << (48 + lr);
      if (bits) atomicOr(&adjtile[wv][rs * 16 + lg * 4 + j], bits);
    }
  }
  int gi = i1 + lane;
  if (gi < S) adj[((size_t)b * Q_ + gi) * WPR + (j1 >> 6)] = adjtile[wv][lane];
}

// ---------------- K4: CC label propagation + best-per-component + compact --
__global__ __launch_bounds__(256)
void k_cc(const float* __restrict__ scores, const int* __restrict__ sel_idx,
          const int* __restrict__ sel_cnt, const u64* __restrict__ adj,
          int* __restrict__ best_idx, float* __restrict__ best_sc,
          int* __restrict__ nroots) {
  int b = blockIdx.x, t = threadIdx.x;
  __shared__ int lab[Q_];
  __shared__ int lab2[Q_];
  __shared__ u64 best[Q_];
  __shared__ int part[256];
  __shared__ int s_changed;

  int S = sel_cnt[b];
  int nw = (S + 63) >> 6;
  const u64* arow0 = adj + (size_t)b * Q_ * WPR;

  for (int s = t; s < S; s += 256) lab[s] = s;
  __syncthreads();

  for (int iter = 0; iter < Q_ + 2; ++iter) {
    if (t == 0) s_changed = 0;
    __syncthreads();
    for (int s = t; s < S; s += 256) {
      int m = lab[s];
      const u64* row = arow0 + (size_t)s * WPR;
      for (int w = 0; w < nw; ++w) {
        u64 msk = row[w];
        while (msk) {
          int j = (w << 6) + __builtin_ctzll(msk);
          int lj = lab[j];
          m = (lj < m) ? lj : m;
          msk &= msk - 1;
        }
      }
      lab2[s] = m;
      if (m != lab[s]) s_changed = 1;   // benign race
    }
    __syncthreads();
    int ch = s_changed;
    for (int s = t; s < S; s += 256) lab[s] = lab2[s];
    __syncthreads();
    if (!ch) break;
  }

  // best member per component root (max score, min original index on tie)
  for (int s = t; s < S; s += 256) best[s] = 0ull;
  __syncthreads();
  const float* scb = scores + b * Q_;
  const int* sidx = sel_idx + b * Q_;
  for (int s = t; s < S; s += 256) {
    int orig = sidx[s];
    float sc = scb[orig];
    u64 key = ((u64)__float_as_uint(sc) << 32) | (u32)(~(u32)orig);
    atomicMax(&best[lab[s]], key);
  }
  __syncthreads();

  // roots (lab[s]==s), prefix-compact in ascending order
  int f[8]; int cnt = 0;
  #pragma unroll
  for (int e = 0; e < 8; ++e) {
    int s = t * 8 + e;
    int fl = (s < S && lab[s] == s) ? 1 : 0;
    f[e] = fl; cnt += fl;
  }
  part[t] = cnt;
  __syncthreads();
  for (int s2 = 1; s2 < 256; s2 <<= 1) {
    int v = (t >= s2) ? part[t - s2] : 0;
    __syncthreads();
    part[t] += v;
    __syncthreads();
  }
  int excl = part[t] - cnt;
  int total = part[255];
  #pragma unroll
  for (int e = 0; e < 8; ++e) {
    if (f[e]) {
      int s = t * 8 + e;
      u64 key = best[s];
      best_idx[b * Q_ + excl] = (int)(~(u32)key);
      best_sc[b * Q_ + excl] = __uint_as_float((u32)(key >> 32));
      excl++;
    }
  }
  if (t == 0) nroots[b] = total;
}

// ---------------- K5: write ALL outputs (sig rows, mask, scores) -----------
__global__ __launch_bounds__(256)
void k_gather(const float* __restrict__ sig, const int* __restrict__ best_idx,
              const float* __restrict__ best_sc, const int* __restrict__ nroots,
              float* __restrict__ out_sig, float* __restrict__ out_mask,
              float* __restrict__ out_scores) {
  int b = blockIdx.y;
  int p = blockIdx.x * 4 + (threadIdx.x >> 6);
  int lane = threadIdx.x & 63;
  if (p >= Q_) return;
  int n = nroots[b];
  float* orow = out_sig + ((size_t)b * Q_ + p) * C_;
  if (p < n) {
    int row = best_idx[b * Q_ + p];
    float4 v = *reinterpret_cast<const float4*>(sig + ((size_t)b * Q_ + row) * C_ + lane * 4);
    *reinterpret_cast<float4*>(orow + lane * 4) = v;
    if (lane == 0) {
      out_mask[b * Q_ + p] = 1.0f;
      out_scores[b * Q_ + p] = best_sc[b * Q_ + p];
    }
  } else {
    *reinterpret_cast<float4*>(orow + lane * 4) = make_float4(0.f, 0.f, 0.f, 0.f);
    if (lane == 0) {
      out_mask[b * Q_ + p] = 0.0f;
      out_scores[b * Q_ + p] = 0.0f;
    }
  }
}

extern "C" void kernel_launch(void* const* d_in, const int* in_sizes, int n_in,
                              void* d_out, int out_size, void* d_ws, size_t ws_size,
                              hipStream_t stream) {
  // defensive input-order resolution
  const float* p0 = (const float*)d_in[0];
  const float* p1 = (const float*)d_in[1];
  const float* sig;  const float* logits;
  if (in_sizes[0] == B_ * Q_ * C_) { sig = p0; logits = p1; }
  else                             { sig = p1; logits = p0; }

  float* out = (float*)d_out;
  float* out_mask   = out + OUT_SIG_ELEMS;
  float* out_scores = out + OUT_SIG_ELEMS + B_ * Q_;

  // small workspace (~0.5 MB)
  char* ws = (char*)d_ws;
  float* scores  = (float*)ws;  ws += B_ * Q_ * 4;
  int* sel_idx   = (int*)ws;    ws += B_ * Q_ * 4;
  int* best_idx  = (int*)ws;    ws += B_ * Q_ * 4;
  float* best_sc = (float*)ws;  ws += B_ * Q_ * 4;
  int* sel_cnt   = (int*)ws;    ws += 256;
  int* nroots    = (int*)ws;    ws += 256;

  // scratch inside d_out (29.7 MB): adj bits [0, 6.68 MB), bf16 nsig at +8 MB
  // (15.2 MB). Both fully rewritten before use each launch; k_gather then
  // overwrites all of d_out with final outputs.
  u64* adj = (u64*)d_out;
  unsigned short* nsig = (unsigned short*)((char*)d_out + (size_t)(8u << 20));

  k_compact<<<B_, 256, 0, stream>>>(logits, scores, sel_idx, sel_cnt);

  dim3 gp(QPAD / 4, B_);
  k_prep<<<gp, 256, 0, stream>>>(sig, sel_idx, sel_cnt, nsig);

  // 1-D grid: batch = lin & 15 pins each batch to an XCD (lin%8 == b%8)
  k_sim<<<B_ * TB_ * TB_, 256, 0, stream>>>(nsig, sel_cnt, adj);

  k_cc<<<B_, 256, 0, stream>>>(scores, sel_idx, sel_cnt, adj, best_idx, best_sc, nroots);

  dim3 gg(Q_ / 4, B_);
  k_gather<<<gg, 256, 0, stream>>>(sig, best_idx, best_sc, nroots,
                                   out, out_mask, out_scores);
}

// Round 7
// 65.608 us; speedup vs baseline: 2.4600x; 1.2665x over previous
//
#include <hip/hip_runtime.h>
#include <hip/hip_bf16.h>
#include <stdint.h>

#define B_ 16
#define Q_ 1800
#define C_ 256
#define WPR 29            // u64 words per adjacency row = ceil(1800/64)
#define QPAD 1856         // WPR*64, padded compacted-row capacity
#define TBK 15            // 128-wide tiles per dim: 15*128 = 1920 >= QPAD
#define OUT_SIG_ELEMS (B_*Q_*C_)

typedef unsigned long long u64;
typedef unsigned int u32;
typedef __attribute__((ext_vector_type(8))) short bf16x8;   // 8 bf16 (4 VGPRs)
typedef __attribute__((ext_vector_type(4))) float f32x4;    // 4 fp32 acc

// ---------------- K1: sigmoid + select + fallback + compact (per batch) ----
__global__ __launch_bounds__(256)
void k_compact(const float* __restrict__ logits, float* __restrict__ scores,
               int* __restrict__ sel_idx, int* __restrict__ sel_cnt) {
  int b = blockIdx.x, t = threadIdx.x;
  __shared__ int part[256];
  __shared__ u64 redk[256];
  const float* lgb = logits + b * Q_;
  float* scb = scores + b * Q_;

  int f[8]; float sv[8]; int cnt = 0; u64 mk = 0;
  #pragma unroll
  for (int e = 0; e < 8; ++e) {
    int q = t * 8 + e;
    int fl = 0; float sc = 0.0f;
    if (q < Q_) {
      sc = 1.0f / (1.0f + expf(-lgb[q]));
      fl = (sc >= 0.5f) ? 1 : 0;
      u64 key = ((u64)__float_as_uint(sc) << 32) | (u32)(~(u32)q); // max score, min idx tie
      mk = (mk > key) ? mk : key;
    }
    f[e] = fl; sv[e] = sc; cnt += fl;
  }
  #pragma unroll
  for (int e = 0; e < 8; ++e) {
    int q = t * 8 + e;
    if (q < Q_) scb[q] = sv[e];
  }
  part[t] = cnt; redk[t] = mk;
  __syncthreads();
  for (int s2 = 128; s2 > 0; s2 >>= 1) {
    if (t < s2) {
      part[t] += part[t + s2];
      redk[t] = (redk[t] > redk[t + s2]) ? redk[t] : redk[t + s2];
    }
    __syncthreads();
  }
  int total_sel = part[0];
  u64 kmax = redk[0];
  __syncthreads();

  if (total_sel == 0) {                    // fallback: argmax-score query
    int fb = (int)(~(u32)kmax);
    if (fb >= t * 8 && fb < t * 8 + 8) f[fb - t * 8] = 1;
  }
  cnt = 0;
  #pragma unroll
  for (int e = 0; e < 8; ++e) cnt += f[e];
  part[t] = cnt;
  __syncthreads();
  for (int s2 = 1; s2 < 256; s2 <<= 1) {   // Hillis-Steele inclusive scan
    int v = (t >= s2) ? part[t - s2] : 0;
    __syncthreads();
    part[t] += v;
    __syncthreads();
  }
  int excl = part[t] - cnt;
  #pragma unroll
  for (int e = 0; e < 8; ++e) {
    if (f[e]) { sel_idx[b * Q_ + excl] = t * 8 + e; excl++; }
  }
  if (t == 255) sel_cnt[b] = part[255];
}

// ---------------- K2: normalize selected rows -> compacted bf16 (pad w/ 0) --
__global__ __launch_bounds__(256)
void k_prep(const float* __restrict__ sig, const int* __restrict__ sel_idx,
            const int* __restrict__ sel_cnt, unsigned short* __restrict__ nsig) {
  int b = blockIdx.y;
  int p = blockIdx.x * 4 + (threadIdx.x >> 6);
  int lane = threadIdx.x & 63;
  int S = sel_cnt[b];
  int Spad = (S + 63) & ~63;
  if (p >= Spad) return;
  unsigned short* dst = nsig + ((size_t)b * QPAD + p) * C_;
  if (p >= S) {                             // zero-pad row
    *reinterpret_cast<uint2*>(dst + lane * 4) = make_uint2(0u, 0u);
    return;
  }
  int row = sel_idx[b * Q_ + p];
  const float* src = sig + ((size_t)b * Q_ + row) * C_;
  float4 v = *reinterpret_cast<const float4*>(src + lane * 4);
  float ss = v.x * v.x + v.y * v.y + v.z * v.z + v.w * v.w;
  #pragma unroll
  for (int m = 32; m; m >>= 1) ss += __shfl_xor(ss, m, 64);
  float inv = 1.0f / fmaxf(sqrtf(ss), 1e-12f);
  __hip_bfloat16 h0 = __float2bfloat16(v.x * inv);
  __hip_bfloat16 h1 = __float2bfloat16(v.y * inv);
  __hip_bfloat16 h2 = __float2bfloat16(v.z * inv);
  __hip_bfloat16 h3 = __float2bfloat16(v.w * inv);
  unsigned short u0, u1, u2, u3;
  __builtin_memcpy(&u0, &h0, 2); __builtin_memcpy(&u1, &h1, 2);
  __builtin_memcpy(&u2, &h2, 2); __builtin_memcpy(&u3, &h3, 2);
  uint2 wv;
  wv.x = (u32)u0 | ((u32)u1 << 16);
  wv.y = (u32)u2 | ((u32)u3 << 16);
  *reinterpret_cast<uint2*>(dst + lane * 4) = wv;
}

// ---------------- K3: LDS-staged MFMA cosine-sim (m97 structure) -----------
// 1-D grid, batch = lin & 15 -> XCD pin (lin%8 == b%8). Block = 128x128 tile,
// 2 K-steps of BK=128. LDS A/B 32KB each, row-XOR swizzle byte^=(row&7)<<4
// (rows stride 256B == bank-aligned; XOR spreads 16 same-lg lanes over 8 bank
// groups -> 2-way = free). Same XOR on ds_write and ds_read (both-sides rule).
// Wave w owns 64x64 subtile at (+64*(w>>1), +64*(w&1)).
// Frag layouts validated bit-exact in rounds 4-6:
//   A lane l: row=l&15, k-slice=(l>>4)*8; B lane l: col=l&15, k-slice=(l>>4)*8;
//   D: col=lane&15, row=(lane>>4)*4+reg.
__global__ __launch_bounds__(256)
void k_sim(const unsigned short* __restrict__ nsig, const int* __restrict__ sel_cnt,
           u64* __restrict__ adj) {
  int lin = blockIdx.x;
  int b = lin & 15;
  int tile = lin >> 4;
  int tib = tile / TBK, tjb = tile - tib * TBK;
  int S = sel_cnt[b];
  if (tib * 128 >= S || tjb * 128 >= S) return;

  __shared__ uint4 Alds[2048];   // 32KB: rows 0..127 x 128 bf16 (swizzled)
  __shared__ uint4 Blds[2048];   // 32KB
  __shared__ u64 adjtile[4][64];

  const int t = threadIdx.x;
  const int wv = t >> 6, lane = t & 63;
  const int lr = lane & 15, lg = lane >> 4;

  const int i1 = tib * 128 + (wv >> 1) * 64;
  const int j1 = tjb * 128 + (wv & 1) * 64;
  const bool live = (i1 < S) && (j1 < S);

  const char* gbase = (const char*)(nsig + (size_t)b * QPAD * C_);
  const char* arow = gbase + (size_t)tib * 128 * 512;   // A-tile row 0, bytes
  const char* brow = gbase + (size_t)tjb * 128 * 512;

  f32x4 acc[4][4];
  #pragma unroll
  for (int rs = 0; rs < 4; ++rs)
    #pragma unroll
    for (int cg = 0; cg < 4; ++cg) acc[rs][cg] = (f32x4){0.f, 0.f, 0.f, 0.f};

  // local row bases for this wave's fragments
  const int ra0 = (wv >> 1) * 64;
  const int rb0 = (wv & 1) * 64;

  for (int kh = 0; kh < 2; ++kh) {
    // ---- stage: 32KB each of A,B; thread t covers 8 x 16B per matrix ----
    #pragma unroll
    for (int it = 0; it < 8; ++it) {
      int o = it * 4096 + t * 16;           // linear byte offset in tile
      int r = o >> 8;                       // tile row (256B per row)
      int w = o & 255;                      // byte within row
      int sw = o ^ ((r & 7) << 4);          // swizzled LDS byte offset
      uint4 va = *reinterpret_cast<const uint4*>(arow + (size_t)r * 512 + kh * 256 + w);
      Alds[sw >> 4] = va;
      uint4 vb = *reinterpret_cast<const uint4*>(brow + (size_t)r * 512 + kh * 256 + w);
      Blds[sw >> 4] = vb;
    }
    __syncthreads();
    if (live) {
      #pragma unroll
      for (int ks = 0; ks < 4; ++ks) {
        bf16x8 af[4], bf[4];
        #pragma unroll
        for (int rs = 0; rs < 4; ++rs) {
          int r = ra0 + rs * 16 + lr;
          int byte = r * 256 + ((ks * 64 + lg * 16) ^ ((r & 7) << 4));
          af[rs] = *reinterpret_cast<const bf16x8*>(
              reinterpret_cast<const char*>(Alds) + byte);
        }
        #pragma unroll
        for (int cg = 0; cg < 4; ++cg) {
          int r = rb0 + cg * 16 + lr;
          int byte = r * 256 + ((ks * 64 + lg * 16) ^ ((r & 7) << 4));
          bf[cg] = *reinterpret_cast<const bf16x8*>(
              reinterpret_cast<const char*>(Blds) + byte);
        }
        #pragma unroll
        for (int rs = 0; rs < 4; ++rs)
          #pragma unroll
          for (int cg = 0; cg < 4; ++cg)
            acc[rs][cg] = __builtin_amdgcn_mfma_f32_16x16x32_bf16(
                af[rs], bf[cg], acc[rs][cg], 0, 0, 0);
      }
    }
    __syncthreads();
  }

  if (!live) return;
  adjtile[wv][lane] = 0ull;              // wave-private strip, wave-ordered
  #pragma unroll
  for (int rs = 0; rs < 4; ++rs) {
    #pragma unroll
    for (int j = 0; j < 4; ++j) {
      u64 bits = 0ull;
      if (acc[rs][0][j] >= 0.8f) bits |= 1ull << (0  + lr);
      if (acc[rs][1][j] >= 0.8f) bits |= 1ull << (16 + lr);
      if (acc[rs][2][j] >= 0.8f) bits |= 1ull << (32 + lr);
      if (acc[rs][3][j] >= 0.8f) bits |= 1ull << (48 + lr);
      if (bits) atomicOr(&adjtile[wv][rs * 16 + lg * 4 + j], bits);
    }
  }
  int gi = i1 + lane;
  if (gi < S) adj[((size_t)b * Q_ + gi) * WPR + (j1 >> 6)] = adjtile[wv][lane];
}

// ---------------- K4: CC label propagation + best-per-component + compact --
__global__ __launch_bounds__(256)
void k_cc(const float* __restrict__ scores, const int* __restrict__ sel_idx,
          const int* __restrict__ sel_cnt, const u64* __restrict__ adj,
          int* __restrict__ best_idx, float* __restrict__ best_sc,
          int* __restrict__ nroots) {
  int b = blockIdx.x, t = threadIdx.x;
  __shared__ int lab[Q_];
  __shared__ int lab2[Q_];
  __shared__ u64 best[Q_];
  __shared__ int part[256];
  __shared__ int s_changed;

  int S = sel_cnt[b];
  int nw = (S + 63) >> 6;
  const u64* arow0 = adj + (size_t)b * Q_ * WPR;

  for (int s = t; s < S; s += 256) lab[s] = s;
  __syncthreads();

  for (int iter = 0; iter < Q_ + 2; ++iter) {
    if (t == 0) s_changed = 0;
    __syncthreads();
    for (int s = t; s < S; s += 256) {
      int m = lab[s];
      const u64* row = arow0 + (size_t)s * WPR;
      for (int w = 0; w < nw; ++w) {
        u64 msk = row[w];
        while (msk) {
          int j = (w << 6) + __builtin_ctzll(msk);
          int lj = lab[j];
          m = (lj < m) ? lj : m;
          msk &= msk - 1;
        }
      }
      lab2[s] = m;
      if (m != lab[s]) s_changed = 1;   // benign race
    }
    __syncthreads();
    int ch = s_changed;
    for (int s = t; s < S; s += 256) lab[s] = lab2[s];
    __syncthreads();
    if (!ch) break;
  }

  // best member per component root (max score, min original index on tie)
  for (int s = t; s < S; s += 256) best[s] = 0ull;
  __syncthreads();
  const float* scb = scores + b * Q_;
  const int* sidx = sel_idx + b * Q_;
  for (int s = t; s < S; s += 256) {
    int orig = sidx[s];
    float sc = scb[orig];
    u64 key = ((u64)__float_as_uint(sc) << 32) | (u32)(~(u32)orig);
    atomicMax(&best[lab[s]], key);
  }
  __syncthreads();

  // roots (lab[s]==s), prefix-compact in ascending order
  int f[8]; int cnt = 0;
  #pragma unroll
  for (int e = 0; e < 8; ++e) {
    int s = t * 8 + e;
    int fl = (s < S && lab[s] == s) ? 1 : 0;
    f[e] = fl; cnt += fl;
  }
  part[t] = cnt;
  __syncthreads();
  for (int s2 = 1; s2 < 256; s2 <<= 1) {
    int v = (t >= s2) ? part[t - s2] : 0;
    __syncthreads();
    part[t] += v;
    __syncthreads();
  }
  int excl = part[t] - cnt;
  int total = part[255];
  #pragma unroll
  for (int e = 0; e < 8; ++e) {
    if (f[e]) {
      int s = t * 8 + e;
      u64 key = best[s];
      best_idx[b * Q_ + excl] = (int)(~(u32)key);
      best_sc[b * Q_ + excl] = __uint_as_float((u32)(key >> 32));
      excl++;
    }
  }
  if (t == 0) nroots[b] = total;
}

// ---------------- K5: write ALL outputs (sig rows, mask, scores) -----------
__global__ __launch_bounds__(256)
void k_gather(const float* __restrict__ sig, const int* __restrict__ best_idx,
              const float* __restrict__ best_sc, const int* __restrict__ nroots,
              float* __restrict__ out_sig, float* __restrict__ out_mask,
              float* __restrict__ out_scores) {
  int b = blockIdx.y;
  int p = blockIdx.x * 4 + (threadIdx.x >> 6);
  int lane = threadIdx.x & 63;
  if (p >= Q_) return;
  int n = nroots[b];
  float* orow = out_sig + ((size_t)b * Q_ + p) * C_;
  if (p < n) {
    int row = best_idx[b * Q_ + p];
    float4 v = *reinterpret_cast<const float4*>(sig + ((size_t)b * Q_ + row) * C_ + lane * 4);
    *reinterpret_cast<float4*>(orow + lane * 4) = v;
    if (lane == 0) {
      out_mask[b * Q_ + p] = 1.0f;
      out_scores[b * Q_ + p] = best_sc[b * Q_ + p];
    }
  } else {
    *reinterpret_cast<float4*>(orow + lane * 4) = make_float4(0.f, 0.f, 0.f, 0.f);
    if (lane == 0) {
      out_mask[b * Q_ + p] = 0.0f;
      out_scores[b * Q_ + p] = 0.0f;
    }
  }
}

extern "C" void kernel_launch(void* const* d_in, const int* in_sizes, int n_in,
                              void* d_out, int out_size, void* d_ws, size_t ws_size,
                              hipStream_t stream) {
  // defensive input-order resolution
  const float* p0 = (const float*)d_in[0];
  const float* p1 = (const float*)d_in[1];
  const float* sig;  const float* logits;
  if (in_sizes[0] == B_ * Q_ * C_) { sig = p0; logits = p1; }
  else                             { sig = p1; logits = p0; }

  float* out = (float*)d_out;
  float* out_mask   = out + OUT_SIG_ELEMS;
  float* out_scores = out + OUT_SIG_ELEMS + B_ * Q_;

  // small workspace (~0.5 MB)
  char* ws = (char*)d_ws;
  float* scores  = (float*)ws;  ws += B_ * Q_ * 4;
  int* sel_idx   = (int*)ws;    ws += B_ * Q_ * 4;
  int* best_idx  = (int*)ws;    ws += B_ * Q_ * 4;
  float* best_sc = (float*)ws;  ws += B_ * Q_ * 4;
  int* sel_cnt   = (int*)ws;    ws += 256;
  int* nroots    = (int*)ws;    ws += 256;

  // scratch inside d_out (29.7 MB): adj bits [0, 6.68 MB), bf16 nsig at +8 MB
  // (15.2 MB). Both fully rewritten before use each launch; k_gather then
  // overwrites all of d_out with final outputs.
  u64* adj = (u64*)d_out;
  unsigned short* nsig = (unsigned short*)((char*)d_out + (size_t)(8u << 20));

  k_compact<<<B_, 256, 0, stream>>>(logits, scores, sel_idx, sel_cnt);

  dim3 gp(QPAD / 4, B_);
  k_prep<<<gp, 256, 0, stream>>>(sig, sel_idx, sel_cnt, nsig);

  // 1-D grid: batch = lin & 15 pins each batch to an XCD (lin%8 == b%8)
  k_sim<<<B_ * TBK * TBK, 256, 0, stream>>>(nsig, sel_cnt, adj);

  k_cc<<<B_, 256, 0, stream>>>(scores, sel_idx, sel_cnt, adj, best_idx, best_sc, nroots);

  dim3 gg(Q_ / 4, B_);
  k_gather<<<gg, 256, 0, stream>>>(sig, best_idx, best_sc, nroots,
                                   out, out_mask, out_scores);
}

// Round 8
// 61.680 us; speedup vs baseline: 2.6166x; 1.0637x over previous
//
#include <hip/hip_runtime.h>
#include <hip/hip_bf16.h>
#include <stdint.h>

#define B_ 16
#define Q_ 1800
#define C_ 256
#define WPR 29            // u64 words per adjacency row = ceil(1800/64)
#define QPAD 1856         // WPR*64, padded compacted-row capacity
#define TBK 15            // 128-wide tiles per dim: 15*128 = 1920 >= QPAD
#define OUT_SIG_ELEMS (B_*Q_*C_)

typedef unsigned long long u64;
typedef unsigned int u32;
typedef __attribute__((ext_vector_type(8))) short bf16x8;   // 8 bf16 (4 VGPRs)
typedef __attribute__((ext_vector_type(4))) float f32x4;    // 4 fp32 acc

// ---------------- K1: sigmoid + select + fallback + compact (per batch) ----
__global__ __launch_bounds__(256)
void k_compact(const float* __restrict__ logits, float* __restrict__ scores,
               int* __restrict__ sel_idx, int* __restrict__ sel_cnt) {
  int b = blockIdx.x, t = threadIdx.x;
  __shared__ int part[256];
  __shared__ u64 redk[256];
  const float* lgb = logits + b * Q_;
  float* scb = scores + b * Q_;

  int f[8]; float sv[8]; int cnt = 0; u64 mk = 0;
  #pragma unroll
  for (int e = 0; e < 8; ++e) {
    int q = t * 8 + e;
    int fl = 0; float sc = 0.0f;
    if (q < Q_) {
      sc = 1.0f / (1.0f + expf(-lgb[q]));
      fl = (sc >= 0.5f) ? 1 : 0;
      u64 key = ((u64)__float_as_uint(sc) << 32) | (u32)(~(u32)q); // max score, min idx tie
      mk = (mk > key) ? mk : key;
    }
    f[e] = fl; sv[e] = sc; cnt += fl;
  }
  #pragma unroll
  for (int e = 0; e < 8; ++e) {
    int q = t * 8 + e;
    if (q < Q_) scb[q] = sv[e];
  }
  part[t] = cnt; redk[t] = mk;
  __syncthreads();
  for (int s2 = 128; s2 > 0; s2 >>= 1) {
    if (t < s2) {
      part[t] += part[t + s2];
      redk[t] = (redk[t] > redk[t + s2]) ? redk[t] : redk[t + s2];
    }
    __syncthreads();
  }
  int total_sel = part[0];
  u64 kmax = redk[0];
  __syncthreads();

  if (total_sel == 0) {                    // fallback: argmax-score query
    int fb = (int)(~(u32)kmax);
    if (fb >= t * 8 && fb < t * 8 + 8) f[fb - t * 8] = 1;
  }
  cnt = 0;
  #pragma unroll
  for (int e = 0; e < 8; ++e) cnt += f[e];
  part[t] = cnt;
  __syncthreads();
  for (int s2 = 1; s2 < 256; s2 <<= 1) {   // Hillis-Steele inclusive scan
    int v = (t >= s2) ? part[t - s2] : 0;
    __syncthreads();
    part[t] += v;
    __syncthreads();
  }
  int excl = part[t] - cnt;
  #pragma unroll
  for (int e = 0; e < 8; ++e) {
    if (f[e]) { sel_idx[b * Q_ + excl] = t * 8 + e; excl++; }
  }
  if (t == 255) sel_cnt[b] = part[255];
}

// ---------------- K2: normalize selected rows -> compacted bf16 (pad w/ 0) --
__global__ __launch_bounds__(256)
void k_prep(const float* __restrict__ sig, const int* __restrict__ sel_idx,
            const int* __restrict__ sel_cnt, unsigned short* __restrict__ nsig) {
  int b = blockIdx.y;
  int p = blockIdx.x * 4 + (threadIdx.x >> 6);
  int lane = threadIdx.x & 63;
  int S = sel_cnt[b];
  int Spad = (S + 63) & ~63;
  if (p >= Spad) return;
  unsigned short* dst = nsig + ((size_t)b * QPAD + p) * C_;
  if (p >= S) {                             // zero-pad row
    *reinterpret_cast<uint2*>(dst + lane * 4) = make_uint2(0u, 0u);
    return;
  }
  int row = sel_idx[b * Q_ + p];
  const float* src = sig + ((size_t)b * Q_ + row) * C_;
  float4 v = *reinterpret_cast<const float4*>(src + lane * 4);
  float ss = v.x * v.x + v.y * v.y + v.z * v.z + v.w * v.w;
  #pragma unroll
  for (int m = 32; m; m >>= 1) ss += __shfl_xor(ss, m, 64);
  float inv = 1.0f / fmaxf(sqrtf(ss), 1e-12f);
  __hip_bfloat16 h0 = __float2bfloat16(v.x * inv);
  __hip_bfloat16 h1 = __float2bfloat16(v.y * inv);
  __hip_bfloat16 h2 = __float2bfloat16(v.z * inv);
  __hip_bfloat16 h3 = __float2bfloat16(v.w * inv);
  unsigned short u0, u1, u2, u3;
  __builtin_memcpy(&u0, &h0, 2); __builtin_memcpy(&u1, &h1, 2);
  __builtin_memcpy(&u2, &h2, 2); __builtin_memcpy(&u3, &h3, 2);
  uint2 wv;
  wv.x = (u32)u0 | ((u32)u1 << 16);
  wv.y = (u32)u2 | ((u32)u3 << 16);
  *reinterpret_cast<uint2*>(dst + lane * 4) = wv;
}

// ---------------- K3: LDS-staged MFMA cosine-sim, TRIANGULAR ---------------
// Only tiles tib<=tjb computed; off-diagonal tiles also write the mirrored
// adjacency word via an in-LDS 64x64 bit-transpose. Coverage: (row r<S,
// word w<nw) is written exactly once by tile (min,max) of (r>>7, w>>1).
// 1-D grid, batch = lin & 15 -> XCD pin. Block = 128x128 tile, 2 K-steps of
// BK=128. LDS row-XOR swizzle byte^=(row&7)<<4 on both write and read.
// Diagonal tiles skip B staging (A tile == B tile).
// Frag layouts validated bit-exact in rounds 4-7.
__global__ __launch_bounds__(256)
void k_sim(const unsigned short* __restrict__ nsig, const int* __restrict__ sel_cnt,
           u64* __restrict__ adj) {
  int lin = blockIdx.x;
  int b = lin & 15;
  int tile = lin >> 4;
  int tib = tile / TBK, tjb = tile - tib * TBK;
  if (tib > tjb) return;                    // symmetric: upper triangle only
  int S = sel_cnt[b];
  if (tjb * 128 >= S || tib * 128 >= S) return;
  const bool diag = (tib == tjb);

  __shared__ uint4 Alds[2048];   // 32KB: rows 0..127 x 128 bf16 (swizzled)
  __shared__ uint4 Blds[2048];   // 32KB
  __shared__ u64 adjtile[4][64];

  const int t = threadIdx.x;
  const int wv = t >> 6, lane = t & 63;
  const int lr = lane & 15, lg = lane >> 4;

  const int i1 = tib * 128 + (wv >> 1) * 64;
  const int j1 = tjb * 128 + (wv & 1) * 64;
  const bool live = (i1 < S) && (j1 < S);

  const char* gbase = (const char*)(nsig + (size_t)b * QPAD * C_);
  const char* arow = gbase + (size_t)tib * 128 * 512;   // A-tile row 0, bytes
  const char* brow = gbase + (size_t)tjb * 128 * 512;

  f32x4 acc[4][4];
  #pragma unroll
  for (int rs = 0; rs < 4; ++rs)
    #pragma unroll
    for (int cg = 0; cg < 4; ++cg) acc[rs][cg] = (f32x4){0.f, 0.f, 0.f, 0.f};

  const int ra0 = (wv >> 1) * 64;
  const int rb0 = (wv & 1) * 64;
  const char* Bbase = reinterpret_cast<const char*>(diag ? Alds : Blds);

  for (int kh = 0; kh < 2; ++kh) {
    // ---- stage: 32KB of A (and B unless diagonal) ----
    #pragma unroll
    for (int it = 0; it < 8; ++it) {
      int o = it * 4096 + t * 16;           // linear byte offset in tile
      int r = o >> 8;                       // tile row (256B per row)
      int w = o & 255;                      // byte within row
      int sw = o ^ ((r & 7) << 4);          // swizzled LDS byte offset
      uint4 va = *reinterpret_cast<const uint4*>(arow + (size_t)r * 512 + kh * 256 + w);
      Alds[sw >> 4] = va;
      if (!diag) {
        uint4 vb = *reinterpret_cast<const uint4*>(brow + (size_t)r * 512 + kh * 256 + w);
        Blds[sw >> 4] = vb;
      }
    }
    __syncthreads();
    if (live) {
      #pragma unroll
      for (int ks = 0; ks < 4; ++ks) {
        bf16x8 af[4], bf[4];
        #pragma unroll
        for (int rs = 0; rs < 4; ++rs) {
          int r = ra0 + rs * 16 + lr;
          int byte = r * 256 + ((ks * 64 + lg * 16) ^ ((r & 7) << 4));
          af[rs] = *reinterpret_cast<const bf16x8*>(
              reinterpret_cast<const char*>(Alds) + byte);
        }
        #pragma unroll
        for (int cg = 0; cg < 4; ++cg) {
          int r = rb0 + cg * 16 + lr;
          int byte = r * 256 + ((ks * 64 + lg * 16) ^ ((r & 7) << 4));
          bf[cg] = *reinterpret_cast<const bf16x8*>(Bbase + byte);
        }
        #pragma unroll
        for (int rs = 0; rs < 4; ++rs)
          #pragma unroll
          for (int cg = 0; cg < 4; ++cg)
            acc[rs][cg] = __builtin_amdgcn_mfma_f32_16x16x32_bf16(
                af[rs], bf[cg], acc[rs][cg], 0, 0, 0);
      }
    }
    __syncthreads();
  }

  if (!live) return;
  adjtile[wv][lane] = 0ull;              // wave-private strip, wave-ordered
  #pragma unroll
  for (int rs = 0; rs < 4; ++rs) {
    #pragma unroll
    for (int j = 0; j < 4; ++j) {
      u64 bits = 0ull;
      if (acc[rs][0][j] >= 0.8f) bits |= 1ull << (0  + lr);
      if (acc[rs][1][j] >= 0.8f) bits |= 1ull << (16 + lr);
      if (acc[rs][2][j] >= 0.8f) bits |= 1ull << (32 + lr);
      if (acc[rs][3][j] >= 0.8f) bits |= 1ull << (48 + lr);
      if (bits) atomicOr(&adjtile[wv][rs * 16 + lg * 4 + j], bits);
    }
  }
  int gi = i1 + lane;
  if (gi < S) adj[((size_t)b * Q_ + gi) * WPR + (j1 >> 6)] = adjtile[wv][lane];

  if (!diag) {
    // mirrored word: 64x64 bit-transpose of this wave's strip.
    // T[lane] bit i = adjtile[i] bit lane (broadcast LDS reads, in-wave order)
    u64 tw = 0ull;
    for (int i = 0; i < 64; ++i)
      tw |= ((adjtile[wv][i] >> lane) & 1ull) << i;
    int gj = j1 + lane;
    if (gj < S) adj[((size_t)b * Q_ + gj) * WPR + (i1 >> 6)] = tw;
  }
}

// ---------------- K4: CC label propagation + best-per-component + compact --
// 1024 threads/block: ~2 elements per thread in every strided loop/scan.
__global__ __launch_bounds__(1024)
void k_cc(const float* __restrict__ scores, const int* __restrict__ sel_idx,
          const int* __restrict__ sel_cnt, const u64* __restrict__ adj,
          int* __restrict__ best_idx, float* __restrict__ best_sc,
          int* __restrict__ nroots) {
  int b = blockIdx.x, t = threadIdx.x;
  __shared__ int lab[Q_];
  __shared__ int lab2[Q_];
  __shared__ u64 best[Q_];
  __shared__ int part[1024];
  __shared__ int s_changed;

  int S = sel_cnt[b];
  int nw = (S + 63) >> 6;
  const u64* arow0 = adj + (size_t)b * Q_ * WPR;

  for (int s = t; s < S; s += 1024) lab[s] = s;
  __syncthreads();

  for (int iter = 0; iter < Q_ + 2; ++iter) {
    if (t == 0) s_changed = 0;
    __syncthreads();
    for (int s = t; s < S; s += 1024) {
      int m = lab[s];
      const u64* row = arow0 + (size_t)s * WPR;
      for (int w = 0; w < nw; ++w) {
        u64 msk = row[w];
        while (msk) {
          int j = (w << 6) + __builtin_ctzll(msk);
          int lj = lab[j];
          m = (lj < m) ? lj : m;
          msk &= msk - 1;
        }
      }
      lab2[s] = m;
      if (m != lab[s]) s_changed = 1;   // benign race
    }
    __syncthreads();
    int ch = s_changed;
    for (int s = t; s < S; s += 1024) lab[s] = lab2[s];
    __syncthreads();
    if (!ch) break;
  }

  // best member per component root (max score, min original index on tie)
  for (int s = t; s < S; s += 1024) best[s] = 0ull;
  __syncthreads();
  const float* scb = scores + b * Q_;
  const int* sidx = sel_idx + b * Q_;
  for (int s = t; s < S; s += 1024) {
    int orig = sidx[s];
    float sc = scb[orig];
    u64 key = ((u64)__float_as_uint(sc) << 32) | (u32)(~(u32)orig);
    atomicMax(&best[lab[s]], key);
  }
  __syncthreads();

  // roots (lab[s]==s), prefix-compact in ascending order
  int f[2]; int cnt = 0;
  #pragma unroll
  for (int e = 0; e < 2; ++e) {
    int s = t * 2 + e;
    int fl = (s < S && lab[s] == s) ? 1 : 0;
    f[e] = fl; cnt += fl;
  }
  part[t] = cnt;
  __syncthreads();
  for (int s2 = 1; s2 < 1024; s2 <<= 1) {
    int v = (t >= s2) ? part[t - s2] : 0;
    __syncthreads();
    part[t] += v;
    __syncthreads();
  }
  int excl = part[t] - cnt;
  int total = part[1023];
  #pragma unroll
  for (int e = 0; e < 2; ++e) {
    if (f[e]) {
      int s = t * 2 + e;
      u64 key = best[s];
      best_idx[b * Q_ + excl] = (int)(~(u32)key);
      best_sc[b * Q_ + excl] = __uint_as_float((u32)(key >> 32));
      excl++;
    }
  }
  if (t == 0) nroots[b] = total;
}

// ---------------- K5: write ALL outputs (sig rows, mask, scores) -----------
__global__ __launch_bounds__(256)
void k_gather(const float* __restrict__ sig, const int* __restrict__ best_idx,
              const float* __restrict__ best_sc, const int* __restrict__ nroots,
              float* __restrict__ out_sig, float* __restrict__ out_mask,
              float* __restrict__ out_scores) {
  int b = blockIdx.y;
  int p = blockIdx.x * 4 + (threadIdx.x >> 6);
  int lane = threadIdx.x & 63;
  if (p >= Q_) return;
  int n = nroots[b];
  float* orow = out_sig + ((size_t)b * Q_ + p) * C_;
  if (p < n) {
    int row = best_idx[b * Q_ + p];
    float4 v = *reinterpret_cast<const float4*>(sig + ((size_t)b * Q_ + row) * C_ + lane * 4);
    *reinterpret_cast<float4*>(orow + lane * 4) = v;
    if (lane == 0) {
      out_mask[b * Q_ + p] = 1.0f;
      out_scores[b * Q_ + p] = best_sc[b * Q_ + p];
    }
  } else {
    *reinterpret_cast<float4*>(orow + lane * 4) = make_float4(0.f, 0.f, 0.f, 0.f);
    if (lane == 0) {
      out_mask[b * Q_ + p] = 0.0f;
      out_scores[b * Q_ + p] = 0.0f;
    }
  }
}

extern "C" void kernel_launch(void* const* d_in, const int* in_sizes, int n_in,
                              void* d_out, int out_size, void* d_ws, size_t ws_size,
                              hipStream_t stream) {
  // defensive input-order resolution
  const float* p0 = (const float*)d_in[0];
  const float* p1 = (const float*)d_in[1];
  const float* sig;  const float* logits;
  if (in_sizes[0] == B_ * Q_ * C_) { sig = p0; logits = p1; }
  else                             { sig = p1; logits = p0; }

  float* out = (float*)d_out;
  float* out_mask   = out + OUT_SIG_ELEMS;
  float* out_scores = out + OUT_SIG_ELEMS + B_ * Q_;

  // small workspace (~0.5 MB)
  char* ws = (char*)d_ws;
  float* scores  = (float*)ws;  ws += B_ * Q_ * 4;
  int* sel_idx   = (int*)ws;    ws += B_ * Q_ * 4;
  int* best_idx  = (int*)ws;    ws += B_ * Q_ * 4;
  float* best_sc = (float*)ws;  ws += B_ * Q_ * 4;
  int* sel_cnt   = (int*)ws;    ws += 256;
  int* nroots    = (int*)ws;    ws += 256;

  // scratch inside d_out (29.7 MB): adj bits [0, 6.68 MB), bf16 nsig at +8 MB
  // (15.2 MB). Both fully rewritten before use each launch; k_gather then
  // overwrites all of d_out with final outputs.
  u64* adj = (u64*)d_out;
  unsigned short* nsig = (unsigned short*)((char*)d_out + (size_t)(8u << 20));

  k_compact<<<B_, 256, 0, stream>>>(logits, scores, sel_idx, sel_cnt);

  dim3 gp(QPAD / 4, B_);
  k_prep<<<gp, 256, 0, stream>>>(sig, sel_idx, sel_cnt, nsig);

  // 1-D grid: batch = lin & 15 pins each batch to an XCD (lin%8 == b%8)
  k_sim<<<B_ * TBK * TBK, 256, 0, stream>>>(nsig, sel_cnt, adj);

  k_cc<<<B_, 1024, 0, stream>>>(scores, sel_idx, sel_cnt, adj, best_idx, best_sc, nroots);

  dim3 gg(Q_ / 4, B_);
  k_gather<<<gg, 256, 0, stream>>>(sig, best_idx, best_sc, nroots,
                                   out, out_mask, out_scores);
}

// Round 9
// 45.205 us; speedup vs baseline: 3.5703x; 1.3645x over previous
//
#include <hip/hip_runtime.h>
#include <hip/hip_bf16.h>
#include <stdint.h>

#define B_ 16
#define Q_ 1800
#define C_ 256
#define WPR 29            // u64 words per adjacency row = ceil(1800/64)
#define QPAD 1856         // WPR*64, padded compacted-row capacity
#define TBK 15            // 128-wide tiles per dim: 15*128 = 1920 >= QPAD
#define OUT_SIG_ELEMS (B_*Q_*C_)

typedef unsigned long long u64;
typedef unsigned int u32;
typedef __attribute__((ext_vector_type(8))) short bf16x8;   // 8 bf16 (4 VGPRs)
typedef __attribute__((ext_vector_type(4))) float f32x4;    // 4 fp32 acc

// ---------------- K1: sigmoid + select + fallback + compact (per batch) ----
// Single shuffle-based scan (2 barriers); max-key reduction only when the
// selection is empty (block-uniform rare path).
__global__ __launch_bounds__(256)
void k_compact(const float* __restrict__ logits, float* __restrict__ scores,
               int* __restrict__ sel_idx, int* __restrict__ sel_cnt) {
  int b = blockIdx.x, t = threadIdx.x;
  int lane = t & 63, wid = t >> 6;
  __shared__ int wsum[4];
  __shared__ int s_tot;
  __shared__ u64 kw[4];
  const float* lgb = logits + b * Q_;
  float* scb = scores + b * Q_;

  int f[8]; int cnt = 0; u64 mk = 0;
  #pragma unroll
  for (int e = 0; e < 8; ++e) {
    int q = t * 8 + e;
    int fl = 0;
    if (q < Q_) {
      float sc = 1.0f / (1.0f + expf(-lgb[q]));
      scb[q] = sc;
      fl = (sc >= 0.5f) ? 1 : 0;
      u64 key = ((u64)__float_as_uint(sc) << 32) | (u32)(~(u32)q); // max score, min idx tie
      mk = (mk > key) ? mk : key;
    }
    f[e] = fl; cnt += fl;
  }

  // wave-level inclusive scan of cnt
  int incl = cnt;
  #pragma unroll
  for (int d = 1; d < 64; d <<= 1) {
    int v = __shfl_up(incl, d, 64);
    if (lane >= d) incl += v;
  }
  if (lane == 63) wsum[wid] = incl;
  __syncthreads();
  if (t == 0) {
    int acc = 0;
    #pragma unroll
    for (int i = 0; i < 4; ++i) { int v = wsum[i]; wsum[i] = acc; acc += v; }
    s_tot = acc;
  }
  __syncthreads();
  int excl = wsum[wid] + incl - cnt;
  int total = s_tot;

  if (total > 0) {
    #pragma unroll
    for (int e = 0; e < 8; ++e) {
      if (f[e]) { sel_idx[b * Q_ + excl] = t * 8 + e; excl++; }
    }
    if (t == 0) sel_cnt[b] = total;
  } else {                                  // fallback: argmax-score query
    u64 r = mk;
    #pragma unroll
    for (int d = 1; d < 64; d <<= 1) {
      u64 o = __shfl_xor(r, d, 64);
      r = (o > r) ? o : r;
    }
    if (lane == 0) kw[wid] = r;
    __syncthreads();
    if (t == 0) {
      u64 m2 = kw[0];
      #pragma unroll
      for (int i = 1; i < 4; ++i) m2 = (kw[i] > m2) ? kw[i] : m2;
      sel_idx[b * Q_] = (int)(~(u32)m2);
      sel_cnt[b] = 1;
    }
  }
}

// ---------------- K2: normalize selected rows -> compacted bf16 (pad w/ 0) --
// Also initializes rowmin[b][p] = UINT_MAX for p < Spad.
__global__ __launch_bounds__(256)
void k_prep(const float* __restrict__ sig, const int* __restrict__ sel_idx,
            const int* __restrict__ sel_cnt, unsigned short* __restrict__ nsig,
            u32* __restrict__ rowmin) {
  int b = blockIdx.y;
  int p = blockIdx.x * 4 + (threadIdx.x >> 6);
  int lane = threadIdx.x & 63;
  int S = sel_cnt[b];
  int Spad = (S + 63) & ~63;
  if (p >= Spad) return;
  if (lane == 0) rowmin[b * QPAD + p] = 0xFFFFFFFFu;
  unsigned short* dst = nsig + ((size_t)b * QPAD + p) * C_;
  if (p >= S) {                             // zero-pad row
    *reinterpret_cast<uint2*>(dst + lane * 4) = make_uint2(0u, 0u);
    return;
  }
  int row = sel_idx[b * Q_ + p];
  const float* src = sig + ((size_t)b * Q_ + row) * C_;
  float4 v = *reinterpret_cast<const float4*>(src + lane * 4);
  float ss = v.x * v.x + v.y * v.y + v.z * v.z + v.w * v.w;
  #pragma unroll
  for (int m = 32; m; m >>= 1) ss += __shfl_xor(ss, m, 64);
  float inv = 1.0f / fmaxf(sqrtf(ss), 1e-12f);
  __hip_bfloat16 h0 = __float2bfloat16(v.x * inv);
  __hip_bfloat16 h1 = __float2bfloat16(v.y * inv);
  __hip_bfloat16 h2 = __float2bfloat16(v.z * inv);
  __hip_bfloat16 h3 = __float2bfloat16(v.w * inv);
  unsigned short u0, u1, u2, u3;
  __builtin_memcpy(&u0, &h0, 2); __builtin_memcpy(&u1, &h1, 2);
  __builtin_memcpy(&u2, &h2, 2); __builtin_memcpy(&u3, &h3, 2);
  uint2 wv;
  wv.x = (u32)u0 | ((u32)u1 << 16);
  wv.y = (u32)u2 | ((u32)u3 << 16);
  *reinterpret_cast<uint2*>(dst + lane * 4) = wv;
}

// ---------------- K3: LDS-staged MFMA cosine-sim, TRIANGULAR ---------------
// Only tiles tib<=tjb computed; off-diagonal tiles also write the mirrored
// adjacency word via an in-LDS 64x64 bit-transpose. Additionally emits
// rowmin[b][row] = min neighbor index (atomicMin) for k_cc's fast path.
// 1-D grid, batch = lin & 15 -> XCD pin. Block = 128x128 tile, 2 K-steps of
// BK=128. LDS row-XOR swizzle byte^=(row&7)<<4 on both write and read.
__global__ __launch_bounds__(256)
void k_sim(const unsigned short* __restrict__ nsig, const int* __restrict__ sel_cnt,
           u64* __restrict__ adj, u32* __restrict__ rowmin) {
  int lin = blockIdx.x;
  int b = lin & 15;
  int tile = lin >> 4;
  int tib = tile / TBK, tjb = tile - tib * TBK;
  if (tib > tjb) return;                    // symmetric: upper triangle only
  int S = sel_cnt[b];
  if (tjb * 128 >= S || tib * 128 >= S) return;
  const bool diag = (tib == tjb);

  __shared__ uint4 Alds[2048];   // 32KB: rows 0..127 x 128 bf16 (swizzled)
  __shared__ uint4 Blds[2048];   // 32KB
  __shared__ u64 adjtile[4][64];

  const int t = threadIdx.x;
  const int wv = t >> 6, lane = t & 63;
  const int lr = lane & 15, lg = lane >> 4;

  const int i1 = tib * 128 + (wv >> 1) * 64;
  const int j1 = tjb * 128 + (wv & 1) * 64;
  const bool live = (i1 < S) && (j1 < S);

  const char* gbase = (const char*)(nsig + (size_t)b * QPAD * C_);
  const char* arow = gbase + (size_t)tib * 128 * 512;   // A-tile row 0, bytes
  const char* brow = gbase + (size_t)tjb * 128 * 512;

  f32x4 acc[4][4];
  #pragma unroll
  for (int rs = 0; rs < 4; ++rs)
    #pragma unroll
    for (int cg = 0; cg < 4; ++cg) acc[rs][cg] = (f32x4){0.f, 0.f, 0.f, 0.f};

  const int ra0 = (wv >> 1) * 64;
  const int rb0 = (wv & 1) * 64;
  const char* Bbase = reinterpret_cast<const char*>(diag ? Alds : Blds);

  for (int kh = 0; kh < 2; ++kh) {
    // ---- stage: 32KB of A (and B unless diagonal) ----
    #pragma unroll
    for (int it = 0; it < 8; ++it) {
      int o = it * 4096 + t * 16;           // linear byte offset in tile
      int r = o >> 8;                       // tile row (256B per row)
      int w = o & 255;                      // byte within row
      int sw = o ^ ((r & 7) << 4);          // swizzled LDS byte offset
      uint4 va = *reinterpret_cast<const uint4*>(arow + (size_t)r * 512 + kh * 256 + w);
      Alds[sw >> 4] = va;
      if (!diag) {
        uint4 vb = *reinterpret_cast<const uint4*>(brow + (size_t)r * 512 + kh * 256 + w);
        Blds[sw >> 4] = vb;
      }
    }
    __syncthreads();
    if (live) {
      #pragma unroll
      for (int ks = 0; ks < 4; ++ks) {
        bf16x8 af[4], bf[4];
        #pragma unroll
        for (int rs = 0; rs < 4; ++rs) {
          int r = ra0 + rs * 16 + lr;
          int byte = r * 256 + ((ks * 64 + lg * 16) ^ ((r & 7) << 4));
          af[rs] = *reinterpret_cast<const bf16x8*>(
              reinterpret_cast<const char*>(Alds) + byte);
        }
        #pragma unroll
        for (int cg = 0; cg < 4; ++cg) {
          int r = rb0 + cg * 16 + lr;
          int byte = r * 256 + ((ks * 64 + lg * 16) ^ ((r & 7) << 4));
          bf[cg] = *reinterpret_cast<const bf16x8*>(Bbase + byte);
        }
        #pragma unroll
        for (int rs = 0; rs < 4; ++rs)
          #pragma unroll
          for (int cg = 0; cg < 4; ++cg)
            acc[rs][cg] = __builtin_amdgcn_mfma_f32_16x16x32_bf16(
                af[rs], bf[cg], acc[rs][cg], 0, 0, 0);
      }
    }
    __syncthreads();
  }

  if (!live) return;
  adjtile[wv][lane] = 0ull;              // wave-private strip, wave-ordered
  #pragma unroll
  for (int rs = 0; rs < 4; ++rs) {
    #pragma unroll
    for (int j = 0; j < 4; ++j) {
      u64 bits = 0ull;
      if (acc[rs][0][j] >= 0.8f) bits |= 1ull << (0  + lr);
      if (acc[rs][1][j] >= 0.8f) bits |= 1ull << (16 + lr);
      if (acc[rs][2][j] >= 0.8f) bits |= 1ull << (32 + lr);
      if (acc[rs][3][j] >= 0.8f) bits |= 1ull << (48 + lr);
      if (bits) atomicOr(&adjtile[wv][rs * 16 + lg * 4 + j], bits);
    }
  }
  int gi = i1 + lane;
  u64 word = adjtile[wv][lane];
  if (gi < S) {
    adj[((size_t)b * Q_ + gi) * WPR + (j1 >> 6)] = word;
    if (word) atomicMin(&rowmin[b * QPAD + gi], (u32)(j1 + __builtin_ctzll(word)));
  }

  if (!diag) {
    // mirrored word: 64x64 bit-transpose of this wave's strip.
    u64 tw = 0ull;
    for (int i = 0; i < 64; ++i)
      tw |= ((adjtile[wv][i] >> lane) & 1ull) << i;
    int gj = j1 + lane;
    if (gj < S) {
      adj[((size_t)b * Q_ + gj) * WPR + (i1 >> 6)] = tw;
      if (tw) atomicMin(&rowmin[b * QPAD + gj], (u32)(i1 + __builtin_ctzll(tw)));
    }
  }
}

// ---------------- K4: CC labels + best-per-component + compact -------------
// Fast path: iteration 0 of min-label propagation == lab[s]=min(s,rowmin[s]).
// If unchanged (generic case), converged without touching the bitmask.
// Fallback: the full verified bitmask loop, seeded by the fast pass.
__global__ __launch_bounds__(1024)
void k_cc(const float* __restrict__ scores, const int* __restrict__ sel_idx,
          const int* __restrict__ sel_cnt, const u64* __restrict__ adj,
          const u32* __restrict__ rowmin,
          int* __restrict__ best_idx, float* __restrict__ best_sc,
          int* __restrict__ nroots) {
  int b = blockIdx.x, t = threadIdx.x;
  int lane = t & 63, wid = t >> 6;
  __shared__ int lab[Q_];
  __shared__ int lab2[Q_];
  __shared__ u64 best[Q_];
  __shared__ int wsum[16];
  __shared__ int s_tot;
  __shared__ int s_changed;

  int S = sel_cnt[b];
  int nw = (S + 63) >> 6;
  const u64* arow0 = adj + (size_t)b * Q_ * WPR;

  // ---- fast pass (== iteration 0 from identity labels) ----
  if (t == 0) s_changed = 0;
  __syncthreads();
  for (int s = t; s < S; s += 1024) {
    u32 m = rowmin[b * QPAD + s];
    u32 v = ((u32)s < m) ? (u32)s : m;
    lab[s] = (int)v;
    if (v != (u32)s) s_changed = 1;        // benign race
  }
  __syncthreads();

  if (s_changed) {
    // ---- full bitmask propagation (verified fallback) ----
    for (int iter = 0; iter < Q_ + 2; ++iter) {
      if (t == 0) s_changed = 0;
      __syncthreads();
      for (int s = t; s < S; s += 1024) {
        int m = lab[s];
        const u64* row = arow0 + (size_t)s * WPR;
        for (int w = 0; w < nw; ++w) {
          u64 msk = row[w];
          while (msk) {
            int j = (w << 6) + __builtin_ctzll(msk);
            int lj = lab[j];
            m = (lj < m) ? lj : m;
            msk &= msk - 1;
          }
        }
        lab2[s] = m;
        if (m != lab[s]) s_changed = 1;   // benign race
      }
      __syncthreads();
      int ch = s_changed;
      for (int s = t; s < S; s += 1024) lab[s] = lab2[s];
      __syncthreads();
      if (!ch) break;
    }
  }

  // best member per component root (max score, min original index on tie)
  for (int s = t; s < S; s += 1024) best[s] = 0ull;
  __syncthreads();
  const float* scb = scores + b * Q_;
  const int* sidx = sel_idx + b * Q_;
  for (int s = t; s < S; s += 1024) {
    int orig = sidx[s];
    float sc = scb[orig];
    u64 key = ((u64)__float_as_uint(sc) << 32) | (u32)(~(u32)orig);
    atomicMax(&best[lab[s]], key);
  }
  __syncthreads();

  // roots (lab[s]==s), shuffle-scan compaction in ascending order
  int f[2]; int cnt = 0;
  #pragma unroll
  for (int e = 0; e < 2; ++e) {
    int s = t * 2 + e;
    int fl = (s < S && lab[s] == s) ? 1 : 0;
    f[e] = fl; cnt += fl;
  }
  int incl = cnt;
  #pragma unroll
  for (int d = 1; d < 64; d <<= 1) {
    int v = __shfl_up(incl, d, 64);
    if (lane >= d) incl += v;
  }
  if (lane == 63) wsum[wid] = incl;
  __syncthreads();
  if (t == 0) {
    int acc = 0;
    #pragma unroll
    for (int i = 0; i < 16; ++i) { int v = wsum[i]; wsum[i] = acc; acc += v; }
    s_tot = acc;
  }
  __syncthreads();
  int excl = wsum[wid] + incl - cnt;
  #pragma unroll
  for (int e = 0; e < 2; ++e) {
    if (f[e]) {
      int s = t * 2 + e;
      u64 key = best[s];
      best_idx[b * Q_ + excl] = (int)(~(u32)key);
      best_sc[b * Q_ + excl] = __uint_as_float((u32)(key >> 32));
      excl++;
    }
  }
  if (t == 0) nroots[b] = s_tot;
}

// ---------------- K5: write ALL outputs (sig rows, mask, scores) -----------
__global__ __launch_bounds__(256)
void k_gather(const float* __restrict__ sig, const int* __restrict__ best_idx,
              const float* __restrict__ best_sc, const int* __restrict__ nroots,
              float* __restrict__ out_sig, float* __restrict__ out_mask,
              float* __restrict__ out_scores) {
  int b = blockIdx.y;
  int p = blockIdx.x * 4 + (threadIdx.x >> 6);
  int lane = threadIdx.x & 63;
  if (p >= Q_) return;
  int n = nroots[b];
  float* orow = out_sig + ((size_t)b * Q_ + p) * C_;
  if (p < n) {
    int row = best_idx[b * Q_ + p];
    float4 v = *reinterpret_cast<const float4*>(sig + ((size_t)b * Q_ + row) * C_ + lane * 4);
    *reinterpret_cast<float4*>(orow + lane * 4) = v;
    if (lane == 0) {
      out_mask[b * Q_ + p] = 1.0f;
      out_scores[b * Q_ + p] = best_sc[b * Q_ + p];
    }
  } else {
    *reinterpret_cast<float4*>(orow + lane * 4) = make_float4(0.f, 0.f, 0.f, 0.f);
    if (lane == 0) {
      out_mask[b * Q_ + p] = 0.0f;
      out_scores[b * Q_ + p] = 0.0f;
    }
  }
}

extern "C" void kernel_launch(void* const* d_in, const int* in_sizes, int n_in,
                              void* d_out, int out_size, void* d_ws, size_t ws_size,
                              hipStream_t stream) {
  // defensive input-order resolution
  const float* p0 = (const float*)d_in[0];
  const float* p1 = (const float*)d_in[1];
  const float* sig;  const float* logits;
  if (in_sizes[0] == B_ * Q_ * C_) { sig = p0; logits = p1; }
  else                             { sig = p1; logits = p0; }

  float* out = (float*)d_out;
  float* out_mask   = out + OUT_SIG_ELEMS;
  float* out_scores = out + OUT_SIG_ELEMS + B_ * Q_;

  // small workspace (~0.5 MB)
  char* ws = (char*)d_ws;
  float* scores  = (float*)ws;  ws += B_ * Q_ * 4;
  int* sel_idx   = (int*)ws;    ws += B_ * Q_ * 4;
  int* best_idx  = (int*)ws;    ws += B_ * Q_ * 4;
  float* best_sc = (float*)ws;  ws += B_ * Q_ * 4;
  int* sel_cnt   = (int*)ws;    ws += 256;
  int* nroots    = (int*)ws;    ws += 256;

  // scratch inside d_out (28.3 MiB total):
  //   adj bits    [0,      6.37 MiB)
  //   bf16 nsig   [8 MiB,  22.5 MiB)
  //   rowmin u32  [26 MiB, 26.12 MiB)
  // All fully (re)initialized before use each launch; k_gather then
  // overwrites all of d_out with final outputs.
  u64* adj = (u64*)d_out;
  unsigned short* nsig = (unsigned short*)((char*)d_out + (size_t)(8u << 20));
  u32* rowmin = (u32*)((char*)d_out + (size_t)(26u << 20));

  k_compact<<<B_, 256, 0, stream>>>(logits, scores, sel_idx, sel_cnt);

  dim3 gp(QPAD / 4, B_);
  k_prep<<<gp, 256, 0, stream>>>(sig, sel_idx, sel_cnt, nsig, rowmin);

  // 1-D grid: batch = lin & 15 pins each batch to an XCD (lin%8 == b%8)
  k_sim<<<B_ * TBK * TBK, 256, 0, stream>>>(nsig, sel_cnt, adj, rowmin);

  k_cc<<<B_, 1024, 0, stream>>>(scores, sel_idx, sel_cnt, adj, rowmin,
                                best_idx, best_sc, nroots);

  dim3 gg(Q_ / 4, B_);
  k_gather<<<gg, 256, 0, stream>>>(sig, best_idx, best_sc, nroots,
                                   out, out_mask, out_scores);
}